// Round 7
// baseline (26240.378 us; speedup 1.0000x reference)
//
#include <hip/hip_runtime.h>
#include <hip/hip_bf16.h>
#include <hip/hip_cooperative_groups.h>

namespace cg = cooperative_groups;

#define Bsz 512
#define Tsz 128
#define Msz 512
#define Psz 512
#define NBLK 256
#define NTHR 512
#define SMEM_BYTES 124992

typedef __attribute__((ext_vector_type(8))) unsigned short ushort8v;

__device__ __forceinline__ float bf2f(unsigned short u) {
    union { unsigned int i; float f; } c; c.i = ((unsigned int)u) << 16; return c.f;
}
__device__ __forceinline__ unsigned short f2bf(float f) {
    union { float f; unsigned int i; } c; c.f = f;
    unsigned int u = c.i;
    unsigned int r = u + 0x7fffu + ((u >> 16) & 1u);
    return (unsigned short)(r >> 16);
}
__device__ __forceinline__ float2 bfpair(unsigned int u) {
    union { unsigned int i; float f; } lo, hi;
    lo.i = u << 16; hi.i = u & 0xffff0000u;
    return make_float2(lo.f, hi.f);
}
__device__ __forceinline__ float fast_tanh(float x) {
    x = fminf(fmaxf(x, -15.f), 15.f);
    float e = __expf(2.f * x);
    return 1.f - 2.f / (e + 1.f);
}
__device__ __forceinline__ float fast_sig(float x) {
    x = fminf(fmaxf(x, -30.f), 30.f);
    return 1.f / (1.f + __expf(-x));
}

// ---------------- Uy = encoded @ U^T, output bf16 (unchanged from baseline) ----------------
__global__ __launch_bounds__(256) void k_uy(const float* __restrict__ A,
                                            const float* __restrict__ U,
                                            unsigned short* __restrict__ C) {
    __shared__ float As[32][68];
    __shared__ float Us[32][68];
    const int tid = threadIdx.x;
    const int tx = tid & 15, ty = tid >> 4;
    const size_t r0 = (size_t)blockIdx.y * 64;
    const int n0 = blockIdx.x * 64;
    float acc[4][4] = {};
    for (int k0 = 0; k0 < 512; k0 += 32) {
#pragma unroll
        for (int i = 0; i < 2; ++i) {
            int f = tid + i * 256;
            int r = f >> 3;
            int kc = (f & 7) * 4;
            float4 v = *reinterpret_cast<const float4*>(&A[(r0 + r) * 512 + k0 + kc]);
            As[kc + 0][r] = v.x; As[kc + 1][r] = v.y; As[kc + 2][r] = v.z; As[kc + 3][r] = v.w;
            float4 w = *reinterpret_cast<const float4*>(&U[(size_t)(n0 + r) * 512 + k0 + kc]);
            Us[kc + 0][r] = w.x; Us[kc + 1][r] = w.y; Us[kc + 2][r] = w.z; Us[kc + 3][r] = w.w;
        }
        __syncthreads();
#pragma unroll
        for (int k = 0; k < 32; ++k) {
            float4 a = *reinterpret_cast<const float4*>(&As[k][ty * 4]);
            float4 b = *reinterpret_cast<const float4*>(&Us[k][tx * 4]);
            float av[4] = {a.x, a.y, a.z, a.w};
            float bv[4] = {b.x, b.y, b.z, b.w};
#pragma unroll
            for (int i = 0; i < 4; ++i)
#pragma unroll
                for (int j = 0; j < 4; ++j)
                    acc[i][j] = fmaf(av[i], bv[j], acc[i][j]);
        }
        __syncthreads();
    }
#pragma unroll
    for (int i = 0; i < 4; ++i) {
        size_t row = r0 + ty * 4 + i;
        ushort4 o;
        o.x = f2bf(acc[i][0]); o.y = f2bf(acc[i][1]);
        o.z = f2bf(acc[i][2]); o.w = f2bf(acc[i][3]);
        *reinterpret_cast<ushort4*>(&C[row * 512 + n0 + tx * 4]) = o;
    }
}

// ---------------- persistent cooperative kernel: all 128 steps ----------------
__global__ __launch_bounds__(NTHR) void k_loop(
    const float* __restrict__ enc, const float* __restrict__ yin,
    const unsigned short* __restrict__ Uyb,
    const float* __restrict__ Wdw, const float* __restrict__ Wdb,
    const float* __restrict__ vdw, const float* __restrict__ wtw,
    const float* __restrict__ wtb,
    const float* __restrict__ Wih, const float* __restrict__ Whh,
    const float* __restrict__ bih, const float* __restrict__ bhh,
    const float* __restrict__ Wyw, const float* __restrict__ Wyb,
    const float* __restrict__ vyw, const float* __restrict__ vyb,
    float* __restrict__ dbuf, float* __restrict__ sbuf, float* __restrict__ x1g,
    float* __restrict__ cb, float* __restrict__ gacc, float* __restrict__ ytl,
    float* __restrict__ out)
{
    cg::grid_group grid = cg::this_grid();
    extern __shared__ char smem[];
    unsigned short* Wd_s  = (unsigned short*)smem;             // [1024 k][16 m] bf16, 32 KB
    unsigned short* Whh_s = (unsigned short*)(smem + 32768);   // [512 k][64 n] bf16, 64 KB
    float* in_s = (float*)(smem + 98304);                      // [64][68] f32 stage, 17.4 KB
    float* x1_s = (float*)(smem + 115712);                     // 512
    float* v_s  = (float*)(smem + 117760);                     // 512
    float* wt_s = (float*)(smem + 119808);                     // 512
    float* bd_s = (float*)(smem + 121856);                     // 512
    float* l_s  = (float*)(smem + 123904);                     // 128
    float* p_s  = (float*)(smem + 124416);                     // 128
    float* r_s  = (float*)(smem + 124928);                     // 16

    const int tid = threadIdx.x;
    const int bid = blockIdx.x;
    const int b0  = (bid >> 5) * 64;   // 8 b-tiles of 64 rows (GEMM phases)
    const int m0  = (bid & 31) * 16;   // x1 m-tile (16 cols)
    const int n0  = (bid & 31) * 64;   // gates n-tile (64 cols of 2048)

    // ---- one-time init ----
    v_s[tid] = vdw[tid]; wt_s[tid] = wtw[tid]; bd_s[tid] = Wdb[tid];
    for (int i = tid; i < 16 * 1024; i += NTHR) {
        int k = i >> 4, ml = i & 15;
        Wd_s[k * 16 + ml] = f2bf(Wdw[(size_t)(m0 + ml) * 1024 + k]);
    }
    for (int i = tid; i < 64 * 512; i += NTHR) {
        int k = i >> 6, nl = i & 63;
        Whh_s[k * 64 + nl] = f2bf(Whh[(size_t)(n0 + nl) * 512 + k]);
    }
    {
        int e = bid * 1024 + tid * 2;
        *(float2*)&dbuf[e] = make_float2(0.f, 0.f);
        *(float2*)&sbuf[e] = make_float2(0.f, 0.f);
    }
    // hoist per-thread LSTM constants (same (b,p) every step)
    const int eu = bid * 1024 + (tid << 1);
    const int ub = eu >> 9, up = eu & 511;
    float2 w_i = *(const float2*)&Wih[up];
    float2 w_f = *(const float2*)&Wih[512 + up];
    float2 w_g = *(const float2*)&Wih[1024 + up];
    float2 w_o = *(const float2*)&Wih[1536 + up];
    float2 c_i, c_f, c_g, c_o;
    {
        float2 a, b;
        a = *(const float2*)&bih[up];        b = *(const float2*)&bhh[up];
        c_i = make_float2(a.x + b.x, a.y + b.y);
        a = *(const float2*)&bih[512 + up];  b = *(const float2*)&bhh[512 + up];
        c_f = make_float2(a.x + b.x, a.y + b.y);
        a = *(const float2*)&bih[1024 + up]; b = *(const float2*)&bhh[1024 + up];
        c_g = make_float2(a.x + b.x, a.y + b.y);
        a = *(const float2*)&bih[1536 + up]; b = *(const float2*)&bhh[1536 + up];
        c_o = make_float2(a.x + b.x, a.y + b.y);
    }
    const float wt512 = wtw[512], wtb0 = wtb[0];
    grid.sync();

    for (int step = 0; step < Tsz; ++step) {
        // ---- PHASE X1: x1 = [d,s] @ W_d^T + b (tile: 64 b x 16 m, K=1024) ----
        {
            const int r = tid >> 3, mc = tid & 7;
            float a0 = 0.f, a1 = 0.f;
            const unsigned int* Wd_u = (const unsigned int*)Wd_s;
            for (int ch = 0; ch < 16; ++ch) {
                const float* src = (ch < 8) ? dbuf : sbuf;
                const int kb = ch * 64, kk0 = (ch & 7) * 64;
                {
                    const int sk = (tid & 7) * 8;
                    const float* g = &src[(size_t)(b0 + r) * 512 + kk0 + sk];
                    float4 u = *(const float4*)g, w = *(const float4*)(g + 4);
                    float* dst = &in_s[r * 68 + sk];
                    *(float4*)dst = u; *(float4*)(dst + 4) = w;
                }
                __syncthreads();
#pragma unroll
                for (int kk = 0; kk < 64; ++kk) {
                    float av = in_s[r * 68 + kk];
                    float2 wf = bfpair(Wd_u[(kb + kk) * 8 + mc]);
                    a0 = fmaf(av, wf.x, a0);
                    a1 = fmaf(av, wf.y, a1);
                }
                __syncthreads();
            }
            const int m = m0 + mc * 2;
            x1g[(size_t)(b0 + r) * 512 + m]     = a0 + bd_s[m];
            x1g[(size_t)(b0 + r) * 512 + m + 1] = a1 + bd_s[m + 1];
        }
        grid.sync();

        // ---- PHASE ATTN: logits/softmax/c_t/y_tilda for rows b=2*bid, 2*bid+1 ----
        for (int rr = 0; rr < 2; ++rr) {
            const int b = bid * 2 + rr;
            x1_s[tid] = x1g[(size_t)b * 512 + tid];
            __syncthreads();
            {
                const int w = tid >> 6, lane = tid & 63, mb = lane * 8;
                float4 xa = *(const float4*)&x1_s[mb];
                float4 xb = *(const float4*)&x1_s[mb + 4];
                float4 va = *(const float4*)&v_s[mb];
                float4 vb2 = *(const float4*)&v_s[mb + 4];
                const unsigned short* ubase = Uyb + (size_t)b * 128 * 512 + mb;
                for (int tt = 0; tt < 16; ++tt) {
                    const int t = w * 16 + tt;
                    ushort8v u = *(const ushort8v*)(ubase + (size_t)t * 512);
                    float s;
                    s  = fast_tanh(bf2f(u[0]) + xa.x) * va.x;
                    s += fast_tanh(bf2f(u[1]) + xa.y) * va.y;
                    s += fast_tanh(bf2f(u[2]) + xa.z) * va.z;
                    s += fast_tanh(bf2f(u[3]) + xa.w) * va.w;
                    s += fast_tanh(bf2f(u[4]) + xb.x) * vb2.x;
                    s += fast_tanh(bf2f(u[5]) + xb.y) * vb2.y;
                    s += fast_tanh(bf2f(u[6]) + xb.z) * vb2.z;
                    s += fast_tanh(bf2f(u[7]) + xb.w) * vb2.w;
#pragma unroll
                    for (int off = 32; off; off >>= 1) s += __shfl_xor(s, off);
                    if (lane == 0) l_s[t] = s;
                }
            }
            __syncthreads();
            if (tid < 64) {
                float v0 = l_s[tid], v1 = l_s[tid + 64];
                float mx = fmaxf(v0, v1);
#pragma unroll
                for (int off = 32; off; off >>= 1) mx = fmaxf(mx, __shfl_xor(mx, off));
                float e0 = __expf(v0 - mx), e1 = __expf(v1 - mx);
                float sm = e0 + e1;
#pragma unroll
                for (int off = 32; off; off >>= 1) sm += __shfl_xor(sm, off);
                float inv = 1.f / sm;
                p_s[tid] = e0 * inv; p_s[tid + 64] = e1 * inv;
            }
            __syncthreads();
            {
                float acc = 0.f;
                const float* eb = enc + (size_t)b * Tsz * Msz + tid;
#pragma unroll 8
                for (int t = 0; t < 128; ++t)
                    acc = fmaf(p_s[t], eb[(size_t)t * 512], acc);
                cb[(size_t)b * 512 + tid] = acc;
                float part = acc * wt_s[tid];
#pragma unroll
                for (int off = 32; off; off >>= 1) part += __shfl_xor(part, off);
                if ((tid & 63) == 0) r_s[tid >> 6] = part;
                __syncthreads();
                if (tid == 0) {
                    float tot = r_s[0] + r_s[1] + r_s[2] + r_s[3] +
                                r_s[4] + r_s[5] + r_s[6] + r_s[7];
                    ytl[b] = tot + yin[(size_t)b * 128 + step] * wt512 + wtb0;
                }
            }
            __syncthreads();
        }

        // ---- PHASE GMM: gacc = d @ W_hh^T (tile: 64 b x 64 n, K=512) ----
        {
            const int r = tid >> 3, nc = tid & 7;
            float fa0 = 0.f, fa1 = 0.f, fa2 = 0.f, fa3 = 0.f,
                  fa4 = 0.f, fa5 = 0.f, fa6 = 0.f, fa7 = 0.f;
            const unsigned int* Wh_u = (const unsigned int*)Whh_s;
            for (int ch = 0; ch < 8; ++ch) {
                const int kb = ch * 64;
                {
                    const int sk = (tid & 7) * 8;
                    const float* g = &dbuf[(size_t)(b0 + r) * 512 + kb + sk];
                    float4 u = *(const float4*)g, w = *(const float4*)(g + 4);
                    float* dst = &in_s[r * 68 + sk];
                    *(float4*)dst = u; *(float4*)(dst + 4) = w;
                }
                __syncthreads();
#pragma unroll
                for (int kk = 0; kk < 64; ++kk) {
                    float av = in_s[r * 68 + kk];
                    uint4 ww = *(const uint4*)&Wh_u[(kb + kk) * 32 + nc * 4];
                    float2 f0 = bfpair(ww.x), f1 = bfpair(ww.y);
                    float2 f2 = bfpair(ww.z), f3 = bfpair(ww.w);
                    fa0 = fmaf(av, f0.x, fa0); fa1 = fmaf(av, f0.y, fa1);
                    fa2 = fmaf(av, f1.x, fa2); fa3 = fmaf(av, f1.y, fa3);
                    fa4 = fmaf(av, f2.x, fa4); fa5 = fmaf(av, f2.y, fa5);
                    fa6 = fmaf(av, f3.x, fa6); fa7 = fmaf(av, f3.y, fa7);
                }
                __syncthreads();
            }
            float* gp = &gacc[(size_t)(b0 + r) * 2048 + n0 + nc * 8];
            *(float4*)gp       = make_float4(fa0, fa1, fa2, fa3);
            *(float4*)(gp + 4) = make_float4(fa4, fa5, fa6, fa7);
        }
        grid.sync();

        // ---- PHASE UPD: LSTM elementwise update (2 elems/thread) ----
        {
            const float* ga = gacc + (size_t)ub * 2048 + up;
            float2 ai = *(const float2*)(ga);
            float2 af = *(const float2*)(ga + 512);
            float2 ag = *(const float2*)(ga + 1024);
            float2 ao = *(const float2*)(ga + 1536);
            float yt = ytl[ub];
            float2 so = *(const float2*)&sbuf[(size_t)ub * 512 + up];
            float i0 = fast_sig(ai.x + yt * w_i.x + c_i.x);
            float i1 = fast_sig(ai.y + yt * w_i.y + c_i.y);
            float f0 = fast_sig(af.x + yt * w_f.x + c_f.x);
            float f1 = fast_sig(af.y + yt * w_f.y + c_f.y);
            float g0 = fast_tanh(ag.x + yt * w_g.x + c_g.x);
            float g1 = fast_tanh(ag.y + yt * w_g.y + c_g.y);
            float o0 = fast_sig(ao.x + yt * w_o.x + c_o.x);
            float o1 = fast_sig(ao.y + yt * w_o.y + c_o.y);
            float s0 = f0 * so.x + i0 * g0;
            float s1 = f1 * so.y + i1 * g1;
            *(float2*)&sbuf[(size_t)ub * 512 + up] = make_float2(s0, s1);
            *(float2*)&dbuf[(size_t)ub * 512 + up] =
                make_float2(o0 * fast_tanh(s0), o1 * fast_tanh(s1));
        }
        grid.sync();
    }

    // ---- PHASE FINAL: out = ([d,c] @ W_y^T + b) @ v_y^T + vb ----
    for (int rr = 0; rr < 2; ++rr) {
        const int b = bid * 2 + rr;
        float* hc = in_s;
        hc[tid] = dbuf[(size_t)b * 512 + tid];
        hc[512 + tid] = cb[(size_t)b * 512 + tid];
        __syncthreads();
        float h = Wyb[tid];
        const float* wr = Wyw + (size_t)tid * 1024;
#pragma unroll 4
        for (int j = 0; j < 1024; j += 4) {
            float4 w4 = *(const float4*)&wr[j];
            h = fmaf(hc[j],     w4.x, h);
            h = fmaf(hc[j + 1], w4.y, h);
            h = fmaf(hc[j + 2], w4.z, h);
            h = fmaf(hc[j + 3], w4.w, h);
        }
        float part = h * vyw[tid];
#pragma unroll
        for (int off = 32; off; off >>= 1) part += __shfl_xor(part, off);
        if ((tid & 63) == 0) r_s[tid >> 6] = part;
        __syncthreads();
        if (tid == 0)
            out[b] = r_s[0] + r_s[1] + r_s[2] + r_s[3] +
                     r_s[4] + r_s[5] + r_s[6] + r_s[7] + vyb[0];
        __syncthreads();
    }
}

extern "C" void kernel_launch(void* const* d_in, const int* in_sizes, int n_in,
                              void* d_out, int out_size, void* d_ws, size_t ws_size,
                              hipStream_t stream) {
    const float* enc = (const float*)d_in[0];
    const float* yin = (const float*)d_in[1];
    const float* Wdw = (const float*)d_in[2];
    const float* Wdb = (const float*)d_in[3];
    const float* Udw = (const float*)d_in[4];
    const float* vdw = (const float*)d_in[5];
    const float* wtw = (const float*)d_in[6];
    const float* wtb = (const float*)d_in[7];
    const float* Wyw = (const float*)d_in[8];
    const float* Wyb = (const float*)d_in[9];
    const float* vyw = (const float*)d_in[10];
    const float* vyb = (const float*)d_in[11];
    const float* Wih = (const float*)d_in[12];
    const float* Whh = (const float*)d_in[13];
    const float* bih = (const float*)d_in[14];
    const float* bhh = (const float*)d_in[15];
    float* out = (float*)d_out;

    // workspace layout
    unsigned short* Uyb = (unsigned short*)d_ws;                    // 64 MiB bf16
    char* p = (char*)d_ws + (size_t)Bsz * Tsz * Msz * 2;
    float* dbuf = (float*)p;                 p += (size_t)Bsz * Psz * 4;
    float* sbuf = (float*)p;                 p += (size_t)Bsz * Psz * 4;
    float* x1g  = (float*)p;                 p += (size_t)Bsz * Msz * 4;
    float* cbuf = (float*)p;                 p += (size_t)Bsz * Msz * 4;
    float* gacc = (float*)p;                 p += (size_t)Bsz * 4 * Psz * 4;
    float* ytl  = (float*)p;                 p += (size_t)Bsz * 4;

    k_uy<<<dim3(Msz / 64, (Bsz * Tsz) / 64), 256, 0, stream>>>(enc, Udw, Uyb);

    hipFuncSetAttribute(reinterpret_cast<const void*>(k_loop),
                        hipFuncAttributeMaxDynamicSharedMemorySize, SMEM_BYTES);
    void* args[] = {
        (void*)&enc, (void*)&yin, (void*)&Uyb, (void*)&Wdw, (void*)&Wdb,
        (void*)&vdw, (void*)&wtw, (void*)&wtb, (void*)&Wih, (void*)&Whh,
        (void*)&bih, (void*)&bhh, (void*)&Wyw, (void*)&Wyb, (void*)&vyw,
        (void*)&vyb, (void*)&dbuf, (void*)&sbuf, (void*)&x1g, (void*)&cbuf,
        (void*)&gacc, (void*)&ytl, (void*)&out};
    hipLaunchCooperativeKernel(reinterpret_cast<void*>(k_loop),
                               dim3(NBLK), dim3(NTHR), args, SMEM_BYTES, stream);
}

// Round 8
// 16162.576 us; speedup vs baseline: 1.6235x; 1.6235x over previous
//
#include <hip/hip_runtime.h>
#include <hip/hip_bf16.h>

#define Bsz 512
#define Tsz 128
#define Msz 512
#define Psz 512

typedef __attribute__((ext_vector_type(8))) unsigned short ushort8v;

__device__ __forceinline__ float h2f(unsigned short u) {
    union { unsigned short u; _Float16 h; } c; c.u = u; return (float)c.h;
}
__device__ __forceinline__ unsigned short f2h(float f) {
    union { unsigned short u; _Float16 h; } c; c.h = (_Float16)f; return c.u;
}
__device__ __forceinline__ float fast_tanh(float x) {
    x = fminf(fmaxf(x, -15.f), 15.f);
    float e = __expf(2.f * x);
    return 1.f - 2.f / (e + 1.f);
}
__device__ __forceinline__ float fast_sig(float x) {
    x = fminf(fmaxf(x, -30.f), 30.f);
    return 1.f / (1.f + __expf(-x));
}

// ---------------- Uy = encoded @ U^T, output fp16 ----------------
__global__ __launch_bounds__(256) void k_uy(const float* __restrict__ A,
                                            const float* __restrict__ U,
                                            unsigned short* __restrict__ C) {
    __shared__ float As[32][68];
    __shared__ float Us[32][68];
    const int tid = threadIdx.x;
    const int tx = tid & 15, ty = tid >> 4;
    const size_t r0 = (size_t)blockIdx.y * 64;
    const int n0 = blockIdx.x * 64;
    float acc[4][4] = {};
    for (int k0 = 0; k0 < 512; k0 += 32) {
#pragma unroll
        for (int i = 0; i < 2; ++i) {
            int f = tid + i * 256;
            int r = f >> 3;
            int kc = (f & 7) * 4;
            float4 v = *reinterpret_cast<const float4*>(&A[(r0 + r) * 512 + k0 + kc]);
            As[kc + 0][r] = v.x; As[kc + 1][r] = v.y; As[kc + 2][r] = v.z; As[kc + 3][r] = v.w;
            float4 w = *reinterpret_cast<const float4*>(&U[(size_t)(n0 + r) * 512 + k0 + kc]);
            Us[kc + 0][r] = w.x; Us[kc + 1][r] = w.y; Us[kc + 2][r] = w.z; Us[kc + 3][r] = w.w;
        }
        __syncthreads();
#pragma unroll
        for (int k = 0; k < 32; ++k) {
            float4 a = *reinterpret_cast<const float4*>(&As[k][ty * 4]);
            float4 b = *reinterpret_cast<const float4*>(&Us[k][tx * 4]);
            float av[4] = {a.x, a.y, a.z, a.w};
            float bv[4] = {b.x, b.y, b.z, b.w};
#pragma unroll
            for (int i = 0; i < 4; ++i)
#pragma unroll
                for (int j = 0; j < 4; ++j)
                    acc[i][j] = fmaf(av[i], bv[j], acc[i][j]);
        }
        __syncthreads();
    }
#pragma unroll
    for (int i = 0; i < 4; ++i) {
        size_t row = r0 + ty * 4 + i;
        ushort4 o;
        o.x = f2h(acc[i][0]); o.y = f2h(acc[i][1]);
        o.z = f2h(acc[i][2]); o.w = f2h(acc[i][3]);
        *reinterpret_cast<ushort4*>(&C[row * 512 + n0 + tx * 4]) = o;
    }
}

// ---------------- enc f32 -> fp16 copy ----------------
__global__ __launch_bounds__(256) void k_e2h(const float* __restrict__ e,
                                             unsigned short* __restrict__ o) {
    size_t i = ((size_t)blockIdx.x * 256 + threadIdx.x) * 8;
    float4 a = *reinterpret_cast<const float4*>(e + i);
    float4 b = *reinterpret_cast<const float4*>(e + i + 4);
    ushort8v r;
    r[0] = f2h(a.x); r[1] = f2h(a.y); r[2] = f2h(a.z); r[3] = f2h(a.w);
    r[4] = f2h(b.x); r[5] = f2h(b.y); r[6] = f2h(b.z); r[7] = f2h(b.w);
    *reinterpret_cast<ushort8v*>(o + i) = r;
}

// ---------------- zero-init d, s ----------------
__global__ void k_zero(float* a, float* b, int n) {
    int i = blockIdx.x * blockDim.x + threadIdx.x;
    if (i < n) { a[i] = 0.f; b[i] = 0.f; }
}

// ---------------- x1 = [d,s] @ W_d_w^T + b (verbatim from validated baseline) ----------------
__global__ __launch_bounds__(256) void k_x1(const float* __restrict__ dcur,
                                            const float* __restrict__ scur,
                                            const float* __restrict__ Wd,
                                            const float* __restrict__ Wdb,
                                            float* __restrict__ x1) {
    __shared__ float Ds[32][36];
    __shared__ float Ws[32][36];
    const int tid = threadIdx.x;
    const int tx = tid & 15, ty = tid >> 4;
    const int m0 = blockIdx.x * 32, b0 = blockIdx.y * 32;
    float acc[2][2] = {};
    for (int k0 = 0; k0 < 1024; k0 += 32) {
        const float* src = (k0 < 512) ? dcur : scur;
        const int kb = k0 & 511;
        {
            int r = tid >> 3, kc = (tid & 7) * 4;
            float4 v = *reinterpret_cast<const float4*>(&src[(size_t)(b0 + r) * 512 + kb + kc]);
            Ds[kc + 0][r] = v.x; Ds[kc + 1][r] = v.y; Ds[kc + 2][r] = v.z; Ds[kc + 3][r] = v.w;
            float4 w = *reinterpret_cast<const float4*>(&Wd[(size_t)(m0 + r) * 1024 + k0 + kc]);
            Ws[kc + 0][r] = w.x; Ws[kc + 1][r] = w.y; Ws[kc + 2][r] = w.z; Ws[kc + 3][r] = w.w;
        }
        __syncthreads();
#pragma unroll
        for (int k = 0; k < 32; ++k) {
            float2 a = *reinterpret_cast<const float2*>(&Ds[k][ty * 2]);
            float2 b = *reinterpret_cast<const float2*>(&Ws[k][tx * 2]);
            acc[0][0] = fmaf(a.x, b.x, acc[0][0]);
            acc[0][1] = fmaf(a.x, b.y, acc[0][1]);
            acc[1][0] = fmaf(a.y, b.x, acc[1][0]);
            acc[1][1] = fmaf(a.y, b.y, acc[1][1]);
        }
        __syncthreads();
    }
#pragma unroll
    for (int i = 0; i < 2; ++i)
#pragma unroll
        for (int j = 0; j < 2; ++j) {
            int m = m0 + tx * 2 + j;
            x1[(size_t)(b0 + ty * 2 + i) * 512 + m] = acc[i][j] + Wdb[m];
        }
}

// ---------------- l[b,t] = sum_m tanh(x1+Uy)*v ; 2 t's per wave ----------------
__global__ __launch_bounds__(256) void k_logits(const unsigned short* __restrict__ Uyh,
                                                const float* __restrict__ x1,
                                                const float* __restrict__ vd,
                                                float* __restrict__ lout) {
    const int lane = threadIdx.x & 63;
    const int u = blockIdx.x * 4 + (threadIdx.x >> 6);  // [0, B*T/2)
    const int b = u >> 6, t0 = u & 63;                  // t1 = t0 + 64 (same b)
    const unsigned short* uy = Uyh + ((size_t)b * 128 + t0) * 512 + lane * 8;
    ushort8v ua = *reinterpret_cast<const ushort8v*>(uy);
    ushort8v ub = *reinterpret_cast<const ushort8v*>(uy + 64 * 512);
    const float* xp = x1 + (size_t)b * 512 + lane * 8;
    const float* vp = vd + lane * 8;
    float4 xa = *reinterpret_cast<const float4*>(xp);
    float4 xb = *reinterpret_cast<const float4*>(xp + 4);
    float4 va = *reinterpret_cast<const float4*>(vp);
    float4 vb = *reinterpret_cast<const float4*>(vp + 4);
    float s0, s1;
    s0  = fast_tanh(h2f(ua[0]) + xa.x) * va.x;
    s0 += fast_tanh(h2f(ua[1]) + xa.y) * va.y;
    s0 += fast_tanh(h2f(ua[2]) + xa.z) * va.z;
    s0 += fast_tanh(h2f(ua[3]) + xa.w) * va.w;
    s0 += fast_tanh(h2f(ua[4]) + xb.x) * vb.x;
    s0 += fast_tanh(h2f(ua[5]) + xb.y) * vb.y;
    s0 += fast_tanh(h2f(ua[6]) + xb.z) * vb.z;
    s0 += fast_tanh(h2f(ua[7]) + xb.w) * vb.w;
    s1  = fast_tanh(h2f(ub[0]) + xa.x) * va.x;
    s1 += fast_tanh(h2f(ub[1]) + xa.y) * va.y;
    s1 += fast_tanh(h2f(ub[2]) + xa.z) * va.z;
    s1 += fast_tanh(h2f(ub[3]) + xa.w) * va.w;
    s1 += fast_tanh(h2f(ub[4]) + xb.x) * vb.x;
    s1 += fast_tanh(h2f(ub[5]) + xb.y) * vb.y;
    s1 += fast_tanh(h2f(ub[6]) + xb.z) * vb.z;
    s1 += fast_tanh(h2f(ub[7]) + xb.w) * vb.w;
#pragma unroll
    for (int off = 32; off; off >>= 1) {
        s0 += __shfl_xor(s0, off);
        s1 += __shfl_xor(s1, off);
    }
    if (lane == 0) {
        lout[b * 128 + t0]      = s0;
        lout[b * 128 + t0 + 64] = s1;
    }
}

// ---------------- softmax + c_t + y_tilda (fp16 enc, 512 thr, wave-per-t) ----------------
__global__ __launch_bounds__(512) void k_smct_h(const float* __restrict__ lin,
                                                const unsigned short* __restrict__ ench,
                                                const float* __restrict__ wt,
                                                const float* __restrict__ wtb,
                                                const float* __restrict__ yin,
                                                float* __restrict__ cout,
                                                float* __restrict__ ytl, int tstep) {
    __shared__ float pacc[8][512];
    __shared__ float sb[128];
    __shared__ float sred[8];
    const int tid = threadIdx.x, b = blockIdx.x;
    if (tid < 128) sb[tid] = lin[b * 128 + tid];
    __syncthreads();
    if (tid < 64) {
        float v0 = sb[tid], v1 = sb[tid + 64];
        float mx = fmaxf(v0, v1);
#pragma unroll
        for (int off = 32; off; off >>= 1) mx = fmaxf(mx, __shfl_xor(mx, off));
        float e0 = __expf(v0 - mx), e1 = __expf(v1 - mx);
        float sm = e0 + e1;
#pragma unroll
        for (int off = 32; off; off >>= 1) sm += __shfl_xor(sm, off);
        float inv = 1.f / sm;
        sb[tid] = e0 * inv; sb[tid + 64] = e1 * inv;
    }
    __syncthreads();
    const int w = tid >> 6, l = tid & 63;
    const unsigned short* eb = ench + (size_t)b * (Tsz * Msz) + l * 8;
    float a0 = 0.f, a1 = 0.f, a2 = 0.f, a3 = 0.f, a4 = 0.f, a5 = 0.f, a6 = 0.f, a7 = 0.f;
#pragma unroll
    for (int tt = 0; tt < 16; ++tt) {
        const int t = tt * 8 + w;
        ushort8v uu = *reinterpret_cast<const ushort8v*>(eb + (size_t)t * 512);
        const float bt = sb[t];
        a0 = fmaf(bt, h2f(uu[0]), a0);
        a1 = fmaf(bt, h2f(uu[1]), a1);
        a2 = fmaf(bt, h2f(uu[2]), a2);
        a3 = fmaf(bt, h2f(uu[3]), a3);
        a4 = fmaf(bt, h2f(uu[4]), a4);
        a5 = fmaf(bt, h2f(uu[5]), a5);
        a6 = fmaf(bt, h2f(uu[6]), a6);
        a7 = fmaf(bt, h2f(uu[7]), a7);
    }
    float* pr = &pacc[w][l * 8];
    *reinterpret_cast<float4*>(pr)     = make_float4(a0, a1, a2, a3);
    *reinterpret_cast<float4*>(pr + 4) = make_float4(a4, a5, a6, a7);
    __syncthreads();
    float c = pacc[0][tid];
#pragma unroll
    for (int ww = 1; ww < 8; ++ww) c += pacc[ww][tid];
    cout[(size_t)b * 512 + tid] = c;
    float part = c * wt[tid];
#pragma unroll
    for (int off = 32; off; off >>= 1) part += __shfl_xor(part, off);
    if (l == 0) sred[w] = part;
    __syncthreads();
    if (tid == 0) {
        float tot = sred[0] + sred[1] + sred[2] + sred[3] +
                    sred[4] + sred[5] + sred[6] + sred[7];
        ytl[b] = tot + yin[(size_t)b * 128 + tstep] * wt[512] + wtb[0];
    }
}

// ---------------- f32-enc fallback (if ws too small for fp16 copy) ----------------
__global__ __launch_bounds__(512) void k_smct_f(const float* __restrict__ lin,
                                                const float* __restrict__ enc,
                                                const float* __restrict__ wt,
                                                const float* __restrict__ wtb,
                                                const float* __restrict__ yin,
                                                float* __restrict__ cout,
                                                float* __restrict__ ytl, int tstep) {
    __shared__ float pacc[8][512];
    __shared__ float sb[128];
    __shared__ float sred[8];
    const int tid = threadIdx.x, b = blockIdx.x;
    if (tid < 128) sb[tid] = lin[b * 128 + tid];
    __syncthreads();
    if (tid < 64) {
        float v0 = sb[tid], v1 = sb[tid + 64];
        float mx = fmaxf(v0, v1);
#pragma unroll
        for (int off = 32; off; off >>= 1) mx = fmaxf(mx, __shfl_xor(mx, off));
        float e0 = __expf(v0 - mx), e1 = __expf(v1 - mx);
        float sm = e0 + e1;
#pragma unroll
        for (int off = 32; off; off >>= 1) sm += __shfl_xor(sm, off);
        float inv = 1.f / sm;
        sb[tid] = e0 * inv; sb[tid + 64] = e1 * inv;
    }
    __syncthreads();
    const int w = tid >> 6, l = tid & 63;
    const float* eb = enc + (size_t)b * (Tsz * Msz) + l * 8;
    float a0 = 0.f, a1 = 0.f, a2 = 0.f, a3 = 0.f, a4 = 0.f, a5 = 0.f, a6 = 0.f, a7 = 0.f;
#pragma unroll
    for (int tt = 0; tt < 16; ++tt) {
        const int t = tt * 8 + w;
        float4 e0v = *reinterpret_cast<const float4*>(eb + (size_t)t * 512);
        float4 e1v = *reinterpret_cast<const float4*>(eb + (size_t)t * 512 + 4);
        const float bt = sb[t];
        a0 = fmaf(bt, e0v.x, a0); a1 = fmaf(bt, e0v.y, a1);
        a2 = fmaf(bt, e0v.z, a2); a3 = fmaf(bt, e0v.w, a3);
        a4 = fmaf(bt, e1v.x, a4); a5 = fmaf(bt, e1v.y, a5);
        a6 = fmaf(bt, e1v.z, a6); a7 = fmaf(bt, e1v.w, a7);
    }
    float* pr = &pacc[w][l * 8];
    *reinterpret_cast<float4*>(pr)     = make_float4(a0, a1, a2, a3);
    *reinterpret_cast<float4*>(pr + 4) = make_float4(a4, a5, a6, a7);
    __syncthreads();
    float c = pacc[0][tid];
#pragma unroll
    for (int ww = 1; ww < 8; ++ww) c += pacc[ww][tid];
    cout[(size_t)b * 512 + tid] = c;
    float part = c * wt[tid];
#pragma unroll
    for (int off = 32; off; off >>= 1) part += __shfl_xor(part, off);
    if (l == 0) sred[w] = part;
    __syncthreads();
    if (tid == 0) {
        float tot = sred[0] + sred[1] + sred[2] + sred[3] +
                    sred[4] + sred[5] + sred[6] + sred[7];
        ytl[b] = tot + yin[(size_t)b * 128 + tstep] * wt[512] + wtb[0];
    }
}

// ---------------- gates GEMM + LSTM update (verbatim from validated baseline) ----------------
__global__ __launch_bounds__(256) void k_gates(const float* __restrict__ dcur,
                                               const float* __restrict__ scur,
                                               const float* __restrict__ Whh,
                                               const float* __restrict__ Wih,
                                               const float* __restrict__ bih,
                                               const float* __restrict__ bhh,
                                               const float* __restrict__ ytl,
                                               float* __restrict__ dnxt,
                                               float* __restrict__ snxt) {
    __shared__ float Ds[32][36];
    __shared__ float Ws[32][132];
    const int tid = threadIdx.x;
    const int tx = tid & 15, ty = tid >> 4;
    const int p0 = blockIdx.x * 32, b0 = blockIdx.y * 32;
    float acc[2][2][4] = {};
    for (int k0 = 0; k0 < 512; k0 += 32) {
        {
            int r = tid >> 3, kc = (tid & 7) * 4;
            float4 v = *reinterpret_cast<const float4*>(&dcur[(size_t)(b0 + r) * 512 + k0 + kc]);
            Ds[kc + 0][r] = v.x; Ds[kc + 1][r] = v.y; Ds[kc + 2][r] = v.z; Ds[kc + 3][r] = v.w;
        }
#pragma unroll
        for (int i = 0; i < 4; ++i) {
            int f = tid + i * 256;
            int row = f >> 3, kc = (f & 7) * 4;
            int g = row >> 5, pc = row & 31;
            float4 w = *reinterpret_cast<const float4*>(&Whh[(size_t)(g * 512 + p0 + pc) * 512 + k0 + kc]);
            Ws[kc + 0][row] = w.x; Ws[kc + 1][row] = w.y; Ws[kc + 2][row] = w.z; Ws[kc + 3][row] = w.w;
        }
        __syncthreads();
#pragma unroll
        for (int k = 0; k < 32; ++k) {
            float2 a = *reinterpret_cast<const float2*>(&Ds[k][ty * 2]);
            float2 w0 = *reinterpret_cast<const float2*>(&Ws[k][tx * 2]);
            float2 w1 = *reinterpret_cast<const float2*>(&Ws[k][32 + tx * 2]);
            float2 w2 = *reinterpret_cast<const float2*>(&Ws[k][64 + tx * 2]);
            float2 w3 = *reinterpret_cast<const float2*>(&Ws[k][96 + tx * 2]);
            acc[0][0][0] = fmaf(a.x, w0.x, acc[0][0][0]);
            acc[0][1][0] = fmaf(a.x, w0.y, acc[0][1][0]);
            acc[1][0][0] = fmaf(a.y, w0.x, acc[1][0][0]);
            acc[1][1][0] = fmaf(a.y, w0.y, acc[1][1][0]);
            acc[0][0][1] = fmaf(a.x, w1.x, acc[0][0][1]);
            acc[0][1][1] = fmaf(a.x, w1.y, acc[0][1][1]);
            acc[1][0][1] = fmaf(a.y, w1.x, acc[1][0][1]);
            acc[1][1][1] = fmaf(a.y, w1.y, acc[1][1][1]);
            acc[0][0][2] = fmaf(a.x, w2.x, acc[0][0][2]);
            acc[0][1][2] = fmaf(a.x, w2.y, acc[0][1][2]);
            acc[1][0][2] = fmaf(a.y, w2.x, acc[1][0][2]);
            acc[1][1][2] = fmaf(a.y, w2.y, acc[1][1][2]);
            acc[0][0][3] = fmaf(a.x, w3.x, acc[0][0][3]);
            acc[0][1][3] = fmaf(a.x, w3.y, acc[0][1][3]);
            acc[1][0][3] = fmaf(a.y, w3.x, acc[1][0][3]);
            acc[1][1][3] = fmaf(a.y, w3.y, acc[1][1][3]);
        }
        __syncthreads();
    }
#pragma unroll
    for (int bi = 0; bi < 2; ++bi)
#pragma unroll
        for (int pj = 0; pj < 2; ++pj) {
            int b = b0 + ty * 2 + bi, p = p0 + tx * 2 + pj;
            float yt = ytl[b];
            float gi = acc[bi][pj][0] + yt * Wih[p] + bih[p] + bhh[p];
            float gf = acc[bi][pj][1] + yt * Wih[512 + p] + bih[512 + p] + bhh[512 + p];
            float gg = acc[bi][pj][2] + yt * Wih[1024 + p] + bih[1024 + p] + bhh[1024 + p];
            float go = acc[bi][pj][3] + yt * Wih[1536 + p] + bih[1536 + p] + bhh[1536 + p];
            float sv = fast_sig(gf) * scur[(size_t)b * 512 + p] + fast_sig(gi) * fast_tanh(gg);
            snxt[(size_t)b * 512 + p] = sv;
            dnxt[(size_t)b * 512 + p] = fast_sig(go) * fast_tanh(sv);
        }
}

// ---------------- final projection (verbatim from validated baseline) ----------------
__global__ __launch_bounds__(256) void k_final(const float* __restrict__ dfin,
                                               const float* __restrict__ cfin,
                                               const float* __restrict__ Wy,
                                               const float* __restrict__ Wyb,
                                               const float* __restrict__ vy,
                                               const float* __restrict__ vyb,
                                               float* __restrict__ out) {
    __shared__ float hc[1024];
    __shared__ float sred[8];
    const int tid = threadIdx.x, b = blockIdx.x;
    hc[tid] = dfin[(size_t)b * 512 + tid];
    hc[256 + tid] = dfin[(size_t)b * 512 + 256 + tid];
    hc[512 + tid] = cfin[(size_t)b * 512 + tid];
    hc[768 + tid] = cfin[(size_t)b * 512 + 256 + tid];
    __syncthreads();
    float part = 0.f;
#pragma unroll
    for (int pi = 0; pi < 2; ++pi) {
        int p = tid + pi * 256;
        float acc = Wyb[p];
        const float* wr = Wy + (size_t)p * 1024;
#pragma unroll 4
        for (int k = 0; k < 1024; k += 4) {
            float4 w = *reinterpret_cast<const float4*>(&wr[k]);
            acc = fmaf(hc[k], w.x, acc);
            acc = fmaf(hc[k + 1], w.y, acc);
            acc = fmaf(hc[k + 2], w.z, acc);
            acc = fmaf(hc[k + 3], w.w, acc);
        }
        part += acc * vy[p];
    }
#pragma unroll
    for (int off = 32; off; off >>= 1) part += __shfl_xor(part, off);
    const int lane = tid & 63, wid = tid >> 6;
    if (lane == 0) sred[wid] = part;
    __syncthreads();
    if (tid == 0) out[b] = sred[0] + sred[1] + sred[2] + sred[3] + vyb[0];
}

extern "C" void kernel_launch(void* const* d_in, const int* in_sizes, int n_in,
                              void* d_out, int out_size, void* d_ws, size_t ws_size,
                              hipStream_t stream) {
    const float* enc = (const float*)d_in[0];
    const float* yin = (const float*)d_in[1];
    const float* Wdw = (const float*)d_in[2];
    const float* Wdb = (const float*)d_in[3];
    const float* Udw = (const float*)d_in[4];
    const float* vdw = (const float*)d_in[5];
    const float* wtw = (const float*)d_in[6];
    const float* wtb = (const float*)d_in[7];
    const float* Wyw = (const float*)d_in[8];
    const float* Wyb = (const float*)d_in[9];
    const float* vyw = (const float*)d_in[10];
    const float* vyb = (const float*)d_in[11];
    const float* Wih = (const float*)d_in[12];
    const float* Whh = (const float*)d_in[13];
    const float* bih = (const float*)d_in[14];
    const float* bhh = (const float*)d_in[15];
    float* out = (float*)d_out;

    // workspace layout: Uy fp16 | f32 scratch | enc fp16 (optional)
    unsigned short* Uyh = (unsigned short*)d_ws;                    // 64 MiB
    char* p = (char*)d_ws + (size_t)Bsz * Tsz * Msz * 2;
    float* dbuf = (float*)p;  p += (size_t)2 * Bsz * Psz * 4;
    float* sbuf = (float*)p;  p += (size_t)2 * Bsz * Psz * 4;
    float* x1b  = (float*)p;  p += (size_t)Bsz * Msz * 4;
    float* lb   = (float*)p;  p += (size_t)Bsz * Tsz * 4;
    float* cb   = (float*)p;  p += (size_t)Bsz * Msz * 4;
    float* ytl  = (float*)p;  p += (size_t)Bsz * 4;
    unsigned short* ench = (unsigned short*)p;
    const size_t need = (size_t)((char*)(ench + (size_t)Bsz * Tsz * Msz) - (char*)d_ws);
    const bool useh = (ws_size >= need);

    k_uy<<<dim3(Msz / 64, (Bsz * Tsz) / 64), 256, 0, stream>>>(enc, Udw, Uyh);
    if (useh)
        k_e2h<<<(Bsz * Tsz * Msz) / (256 * 8), 256, 0, stream>>>(enc, ench);
    k_zero<<<(Bsz * Psz + 255) / 256, 256, 0, stream>>>(dbuf, sbuf, Bsz * Psz);

    for (int t = 0; t < Tsz; ++t) {
        float* dc = dbuf + (t & 1) * (Bsz * Psz);
        float* sc = sbuf + (t & 1) * (Bsz * Psz);
        float* dn = dbuf + ((t & 1) ^ 1) * (Bsz * Psz);
        float* sn = sbuf + ((t & 1) ^ 1) * (Bsz * Psz);
        k_x1<<<dim3(16, 16), 256, 0, stream>>>(dc, sc, Wdw, Wdb, x1b);
        k_logits<<<(Bsz * Tsz) / 8, 256, 0, stream>>>(Uyh, x1b, vdw, lb);
        if (useh)
            k_smct_h<<<Bsz, 512, 0, stream>>>(lb, ench, wtw, wtb, yin, cb, ytl, t);
        else
            k_smct_f<<<Bsz, 512, 0, stream>>>(lb, enc, wtw, wtb, yin, cb, ytl, t);
        k_gates<<<dim3(16, 16), 256, 0, stream>>>(dc, sc, Whh, Wih, bih, bhh, ytl, dn, sn);
    }
    // after 128 steps the live buffers are parity 0
    k_final<<<Bsz, 256, 0, stream>>>(dbuf, cb, Wyw, Wyb, vyw, vyb, out);
}

// Round 10
// 7515.816 us; speedup vs baseline: 3.4914x; 2.1505x over previous
//
#include <hip/hip_runtime.h>
#include <hip/hip_bf16.h>

#define Bsz 512
#define Tsz 128
#define Msz 512
#define Psz 512

typedef __attribute__((ext_vector_type(8))) unsigned short ushort8v;
typedef __attribute__((ext_vector_type(8))) short short8v;
typedef __attribute__((ext_vector_type(4))) float floatx4;

__device__ __forceinline__ float h2f(unsigned short u) {
    union { unsigned short u; _Float16 h; } c; c.u = u; return (float)c.h;
}
__device__ __forceinline__ unsigned short f2h(float f) {
    union { unsigned short u; _Float16 h; } c; c.h = (_Float16)f; return c.u;
}
__device__ __forceinline__ unsigned short f2bf(float f) {
    union { float f; unsigned int i; } c; c.f = f;
    unsigned int u = c.i;
    unsigned int r = u + 0x7fffu + ((u >> 16) & 1u);
    return (unsigned short)(r >> 16);
}
__device__ __forceinline__ float fast_tanh(float x) {
    x = fminf(fmaxf(x, -15.f), 15.f);
    float e = __expf(2.f * x);
    return 1.f - 2.f / (e + 1.f);
}
__device__ __forceinline__ float fast_sig(float x) {
    x = fminf(fmaxf(x, -30.f), 30.f);
    return 1.f / (1.f + __expf(-x));
}

// ---------------- Uy = encoded @ U^T, output fp16 (validated r8) ----------------
__global__ __launch_bounds__(256) void k_uy(const float* __restrict__ A,
                                            const float* __restrict__ U,
                                            unsigned short* __restrict__ C) {
    __shared__ float As[32][68];
    __shared__ float Us[32][68];
    const int tid = threadIdx.x;
    const int tx = tid & 15, ty = tid >> 4;
    const size_t r0 = (size_t)blockIdx.y * 64;
    const int n0 = blockIdx.x * 64;
    float acc[4][4] = {};
    for (int k0 = 0; k0 < 512; k0 += 32) {
#pragma unroll
        for (int i = 0; i < 2; ++i) {
            int f = tid + i * 256;
            int r = f >> 3;
            int kc = (f & 7) * 4;
            float4 v = *reinterpret_cast<const float4*>(&A[(r0 + r) * 512 + k0 + kc]);
            As[kc + 0][r] = v.x; As[kc + 1][r] = v.y; As[kc + 2][r] = v.z; As[kc + 3][r] = v.w;
            float4 w = *reinterpret_cast<const float4*>(&U[(size_t)(n0 + r) * 512 + k0 + kc]);
            Us[kc + 0][r] = w.x; Us[kc + 1][r] = w.y; Us[kc + 2][r] = w.z; Us[kc + 3][r] = w.w;
        }
        __syncthreads();
#pragma unroll
        for (int k = 0; k < 32; ++k) {
            float4 a = *reinterpret_cast<const float4*>(&As[k][ty * 4]);
            float4 b = *reinterpret_cast<const float4*>(&Us[k][tx * 4]);
            float av[4] = {a.x, a.y, a.z, a.w};
            float bv[4] = {b.x, b.y, b.z, b.w};
#pragma unroll
            for (int i = 0; i < 4; ++i)
#pragma unroll
                for (int j = 0; j < 4; ++j)
                    acc[i][j] = fmaf(av[i], bv[j], acc[i][j]);
        }
        __syncthreads();
    }
#pragma unroll
    for (int i = 0; i < 4; ++i) {
        size_t row = r0 + ty * 4 + i;
        ushort4 o;
        o.x = f2h(acc[i][0]); o.y = f2h(acc[i][1]);
        o.z = f2h(acc[i][2]); o.w = f2h(acc[i][3]);
        *reinterpret_cast<ushort4*>(&C[row * 512 + n0 + tx * 4]) = o;
    }
}

// ---------------- enc f32 -> fp16 copy (validated r8) ----------------
__global__ __launch_bounds__(256) void k_e2h(const float* __restrict__ e,
                                             unsigned short* __restrict__ o) {
    size_t i = ((size_t)blockIdx.x * 256 + threadIdx.x) * 8;
    float4 a = *reinterpret_cast<const float4*>(e + i);
    float4 b = *reinterpret_cast<const float4*>(e + i + 4);
    ushort8v r;
    r[0] = f2h(a.x); r[1] = f2h(a.y); r[2] = f2h(a.z); r[3] = f2h(a.w);
    r[4] = f2h(b.x); r[5] = f2h(b.y); r[6] = f2h(b.z); r[7] = f2h(b.w);
    *reinterpret_cast<ushort8v*>(o + i) = r;
}

// ---------------- weights -> bf16: W16 = [Whh(2048) | Wd[:,:512](512) | Wd[:,512:](512)] x 512k ----
__global__ __launch_bounds__(256) void k_w2b(const float* __restrict__ Whh,
                                             const float* __restrict__ Wdw,
                                             unsigned short* __restrict__ W16) {
    size_t o = ((size_t)blockIdx.x * 256 + threadIdx.x) * 8;   // 3072*512 elems total
    int row = (int)(o >> 9), k = (int)(o & 511);
    const float* src;
    if (row < 2048)      src = &Whh[(size_t)row * 512 + k];
    else if (row < 2560) src = &Wdw[(size_t)(row - 2048) * 1024 + k];
    else                 src = &Wdw[(size_t)(row - 2560) * 1024 + 512 + k];
    float4 a = *reinterpret_cast<const float4*>(src);
    float4 b = *reinterpret_cast<const float4*>(src + 4);
    ushort8v r;
    r[0] = f2bf(a.x); r[1] = f2bf(a.y); r[2] = f2bf(a.z); r[3] = f2bf(a.w);
    r[4] = f2bf(b.x); r[5] = f2bf(b.y); r[6] = f2bf(b.z); r[7] = f2bf(b.w);
    *reinterpret_cast<ushort8v*>(W16 + o) = r;
}

// ---------------- zero-init states (f32 + bf16) ----------------
__global__ void k_zero(float* a, float* b, unsigned short* ah, unsigned short* bh, int n) {
    int i = blockIdx.x * blockDim.x + threadIdx.x;
    if (i < n) { a[i] = 0.f; b[i] = 0.f; ah[i] = 0; bh[i] = 0; }
}

// ---------------- K1: MFMA GEMM — gates gacc = d@Whh^T  and  x1 = d@WdA^T + s@WdB^T + bias ----
__global__ __launch_bounds__(256) void k_mm(const unsigned short* __restrict__ dbh,
                                            const unsigned short* __restrict__ sbh,
                                            const unsigned short* __restrict__ W16,
                                            const float* __restrict__ Wdb,
                                            float* __restrict__ gacc,
                                            float* __restrict__ x1g) {
    __shared__ unsigned short As[64][48];   // 64 rows x 32 k bf16; pitch 96 B (16B-aligned)
    __shared__ unsigned short Ws[64][48];
    const int tid = threadIdx.x;
    const int lane = tid & 63, w = tid >> 6;
    const int rbw = (w >> 1) * 32, cbw = (w & 1) * 32;   // wave quadrant of 64x64 tile
    const int b0 = blockIdx.y * 64;
    const int n0 = blockIdx.x * 64;                      // [0,2048) gates, [2048,2560) x1
    const bool isx1 = (n0 >= 2048);
    const int l15 = lane & 15, kq = (lane >> 4) * 8;
    floatx4 acc00 = {}, acc01 = {}, acc10 = {}, acc11 = {};

    const int npass = isx1 ? 2 : 1;
    for (int pass = 0; pass < npass; ++pass) {
        const unsigned short* Ab = (pass == 0) ? dbh : sbh;
        const unsigned short* Wb = W16 + (size_t)(pass == 0 ? n0 : n0 + 512) * 512;
        for (int k0 = 0; k0 < 512; k0 += 32) {
            {
                const int r = tid >> 2, kc = (tid & 3) * 8;
                *reinterpret_cast<ushort8v*>(&As[r][kc]) =
                    *reinterpret_cast<const ushort8v*>(&Ab[(size_t)(b0 + r) * 512 + k0 + kc]);
                *reinterpret_cast<ushort8v*>(&Ws[r][kc]) =
                    *reinterpret_cast<const ushort8v*>(&Wb[(size_t)r * 512 + k0 + kc]);
            }
            __syncthreads();
            short8v a0 = *reinterpret_cast<const short8v*>(&As[rbw + l15][kq]);
            short8v a1 = *reinterpret_cast<const short8v*>(&As[rbw + 16 + l15][kq]);
            short8v q0 = *reinterpret_cast<const short8v*>(&Ws[cbw + l15][kq]);
            short8v q1 = *reinterpret_cast<const short8v*>(&Ws[cbw + 16 + l15][kq]);
            acc00 = __builtin_amdgcn_mfma_f32_16x16x32_bf16(a0, q0, acc00, 0, 0, 0);
            acc01 = __builtin_amdgcn_mfma_f32_16x16x32_bf16(a0, q1, acc01, 0, 0, 0);
            acc10 = __builtin_amdgcn_mfma_f32_16x16x32_bf16(a1, q0, acc10, 0, 0, 0);
            acc11 = __builtin_amdgcn_mfma_f32_16x16x32_bf16(a1, q1, acc11, 0, 0, 0);
            __syncthreads();
        }
    }
    // C/D layout (verified): col = lane&15, row = (lane>>4)*4 + reg
    const int rB = rbw + (lane >> 4) * 4;
#pragma unroll
    for (int fr = 0; fr < 2; ++fr)
#pragma unroll
        for (int fc = 0; fc < 2; ++fc) {
            const floatx4 av = fr ? (fc ? acc11 : acc10) : (fc ? acc01 : acc00);
            const int col = cbw + fc * 16 + l15;
#pragma unroll
            for (int i = 0; i < 4; ++i) {
                const int row = b0 + rB + fr * 16 + i;
                if (!isx1) {
                    gacc[(size_t)row * 2048 + n0 + col] = av[i];
                } else {
                    const int m = (n0 - 2048) + col;
                    x1g[(size_t)row * 512 + m] = av[i] + Wdb[m];
                }
            }
        }
}

// ---------------- K2: fused attention per b: logits+softmax+c_t+y_tilda ----------------
__global__ __launch_bounds__(512) void k_attn(const unsigned short* __restrict__ Uyh,
                                              const unsigned short* __restrict__ ench,
                                              const float* __restrict__ encf,
                                              const float* __restrict__ x1g,
                                              const float* __restrict__ vd,
                                              const float* __restrict__ wt,
                                              const float* __restrict__ wtb,
                                              const float* __restrict__ yin,
                                              float* __restrict__ cout,
                                              float* __restrict__ ytl,
                                              int tstep, int useh) {
    __shared__ float x1_s[512];
    __shared__ float l_s[128];
    __shared__ float pacc[8][512];
    __shared__ float sred[8];
    const int tid = threadIdx.x, b = blockIdx.x;
    const int w = tid >> 6, lane = tid & 63;
    x1_s[tid] = x1g[(size_t)b * 512 + tid];
    __syncthreads();
    // logits: wave w -> t = w*16 + tt   (validated r7 phase)
    {
        const int mb = lane * 8;
        float4 xa = *reinterpret_cast<const float4*>(&x1_s[mb]);
        float4 xb = *reinterpret_cast<const float4*>(&x1_s[mb + 4]);
        float4 va = *reinterpret_cast<const float4*>(&vd[mb]);
        float4 vb = *reinterpret_cast<const float4*>(&vd[mb + 4]);
        const unsigned short* ubase = Uyh + (size_t)b * 128 * 512 + mb;
        for (int tt = 0; tt < 16; ++tt) {
            const int t = w * 16 + tt;
            ushort8v u = *reinterpret_cast<const ushort8v*>(ubase + (size_t)t * 512);
            float s;
            s  = fast_tanh(h2f(u[0]) + xa.x) * va.x;
            s += fast_tanh(h2f(u[1]) + xa.y) * va.y;
            s += fast_tanh(h2f(u[2]) + xa.z) * va.z;
            s += fast_tanh(h2f(u[3]) + xa.w) * va.w;
            s += fast_tanh(h2f(u[4]) + xb.x) * vb.x;
            s += fast_tanh(h2f(u[5]) + xb.y) * vb.y;
            s += fast_tanh(h2f(u[6]) + xb.z) * vb.z;
            s += fast_tanh(h2f(u[7]) + xb.w) * vb.w;
#pragma unroll
            for (int off = 32; off; off >>= 1) s += __shfl_xor(s, off);
            if (lane == 0) l_s[t] = s;
        }
    }
    __syncthreads();
    // softmax over 128 (validated r8 pattern)
    if (tid < 64) {
        float v0 = l_s[tid], v1 = l_s[tid + 64];
        float mx = fmaxf(v0, v1);
#pragma unroll
        for (int off = 32; off; off >>= 1) mx = fmaxf(mx, __shfl_xor(mx, off));
        float e0 = __expf(v0 - mx), e1 = __expf(v1 - mx);
        float sm = e0 + e1;
#pragma unroll
        for (int off = 32; off; off >>= 1) sm += __shfl_xor(sm, off);
        float inv = 1.f / sm;
        l_s[tid] = e0 * inv; l_s[tid + 64] = e1 * inv;
    }
    __syncthreads();
    // c_t: wave-per-t chunks (validated r8 pattern)
    float a0 = 0.f, a1 = 0.f, a2 = 0.f, a3 = 0.f, a4 = 0.f, a5 = 0.f, a6 = 0.f, a7 = 0.f;
    if (useh) {
        const unsigned short* eb = ench + (size_t)b * (Tsz * Msz) + lane * 8;
#pragma unroll
        for (int tt = 0; tt < 16; ++tt) {
            const int t = tt * 8 + w;
            ushort8v uu = *reinterpret_cast<const ushort8v*>(eb + (size_t)t * 512);
            const float bt = l_s[t];
            a0 = fmaf(bt, h2f(uu[0]), a0); a1 = fmaf(bt, h2f(uu[1]), a1);
            a2 = fmaf(bt, h2f(uu[2]), a2); a3 = fmaf(bt, h2f(uu[3]), a3);
            a4 = fmaf(bt, h2f(uu[4]), a4); a5 = fmaf(bt, h2f(uu[5]), a5);
            a6 = fmaf(bt, h2f(uu[6]), a6); a7 = fmaf(bt, h2f(uu[7]), a7);
        }
    } else {
        const float* eb = encf + (size_t)b * (Tsz * Msz) + lane * 8;
#pragma unroll
        for (int tt = 0; tt < 16; ++tt) {
            const int t = tt * 8 + w;
            float4 e0 = *reinterpret_cast<const float4*>(eb + (size_t)t * 512);
            float4 e1 = *reinterpret_cast<const float4*>(eb + (size_t)t * 512 + 4);
            const float bt = l_s[t];
            a0 = fmaf(bt, e0.x, a0); a1 = fmaf(bt, e0.y, a1);
            a2 = fmaf(bt, e0.z, a2); a3 = fmaf(bt, e0.w, a3);
            a4 = fmaf(bt, e1.x, a4); a5 = fmaf(bt, e1.y, a5);
            a6 = fmaf(bt, e1.z, a6); a7 = fmaf(bt, e1.w, a7);
        }
    }
    float* pr = &pacc[w][lane * 8];
    *reinterpret_cast<float4*>(pr)     = make_float4(a0, a1, a2, a3);
    *reinterpret_cast<float4*>(pr + 4) = make_float4(a4, a5, a6, a7);
    __syncthreads();
    float c = pacc[0][tid];
#pragma unroll
    for (int ww = 1; ww < 8; ++ww) c += pacc[ww][tid];
    cout[(size_t)b * 512 + tid] = c;
    float part = c * wt[tid];
#pragma unroll
    for (int off = 32; off; off >>= 1) part += __shfl_xor(part, off);
    if (lane == 0) sred[w] = part;
    __syncthreads();
    if (tid == 0) {
        float tot = sred[0] + sred[1] + sred[2] + sred[3] +
                    sred[4] + sred[5] + sred[6] + sred[7];
        ytl[b] = tot + yin[(size_t)b * 128 + tstep] * wt[512] + wtb[0];
    }
}

// ---------------- K3: LSTM elementwise update (validated r7 logic) ----------------
__global__ __launch_bounds__(256) void k_upd(const float* __restrict__ gacc,
                                             const float* __restrict__ ytl,
                                             const float* __restrict__ Wih,
                                             const float* __restrict__ bih,
                                             const float* __restrict__ bhh,
                                             const float* __restrict__ scur,
                                             float* __restrict__ snxt,
                                             float* __restrict__ dnxt,
                                             unsigned short* __restrict__ snh,
                                             unsigned short* __restrict__ dnh) {
    const int e = blockIdx.x * 256 + threadIdx.x;   // [0, B*P)
    const int b = e >> 9, p = e & 511;
    const float yt = ytl[b];
    const float* ga = gacc + (size_t)b * 2048;
    float gi = ga[p]        + yt * Wih[p]        + bih[p]        + bhh[p];
    float gf = ga[512 + p]  + yt * Wih[512 + p]  + bih[512 + p]  + bhh[512 + p];
    float gg = ga[1024 + p] + yt * Wih[1024 + p] + bih[1024 + p] + bhh[1024 + p];
    float go = ga[1536 + p] + yt * Wih[1536 + p] + bih[1536 + p] + bhh[1536 + p];
    float sv = fast_sig(gf) * scur[e] + fast_sig(gi) * fast_tanh(gg);
    float dv = fast_sig(go) * fast_tanh(sv);
    snxt[e] = sv; dnxt[e] = dv;
    snh[e] = f2bf(sv); dnh[e] = f2bf(dv);
}

// ---------------- final projection (validated r3) ----------------
__global__ __launch_bounds__(256) void k_final(const float* __restrict__ dfin,
                                               const float* __restrict__ cfin,
                                               const float* __restrict__ Wy,
                                               const float* __restrict__ Wyb,
                                               const float* __restrict__ vy,
                                               const float* __restrict__ vyb,
                                               float* __restrict__ out) {
    __shared__ float hc[1024];
    __shared__ float sred[8];
    const int tid = threadIdx.x, b = blockIdx.x;
    hc[tid] = dfin[(size_t)b * 512 + tid];
    hc[256 + tid] = dfin[(size_t)b * 512 + 256 + tid];
    hc[512 + tid] = cfin[(size_t)b * 512 + tid];
    hc[768 + tid] = cfin[(size_t)b * 512 + 256 + tid];
    __syncthreads();
    float part = 0.f;
#pragma unroll
    for (int pi = 0; pi < 2; ++pi) {
        int p = tid + pi * 256;
        float acc = Wyb[p];
        const float* wr = Wy + (size_t)p * 1024;
#pragma unroll 4
        for (int k = 0; k < 1024; k += 4) {
            float4 w = *reinterpret_cast<const float4*>(&wr[k]);
            acc = fmaf(hc[k], w.x, acc);
            acc = fmaf(hc[k + 1], w.y, acc);
            acc = fmaf(hc[k + 2], w.z, acc);
            acc = fmaf(hc[k + 3], w.w, acc);
        }
        part += acc * vy[p];
    }
#pragma unroll
    for (int off = 32; off; off >>= 1) part += __shfl_xor(part, off);
    const int lane = tid & 63, wid = tid >> 6;
    if (lane == 0) sred[wid] = part;
    __syncthreads();
    if (tid == 0) out[b] = sred[0] + sred[1] + sred[2] + sred[3] + vyb[0];
}

extern "C" void kernel_launch(void* const* d_in, const int* in_sizes, int n_in,
                              void* d_out, int out_size, void* d_ws, size_t ws_size,
                              hipStream_t stream) {
    const float* enc = (const float*)d_in[0];
    const float* yin = (const float*)d_in[1];
    const float* Wdw = (const float*)d_in[2];
    const float* Wdb = (const float*)d_in[3];
    const float* Udw = (const float*)d_in[4];
    const float* vdw = (const float*)d_in[5];
    const float* wtw = (const float*)d_in[6];
    const float* wtb = (const float*)d_in[7];
    const float* Wyw = (const float*)d_in[8];
    const float* Wyb = (const float*)d_in[9];
    const float* vyw = (const float*)d_in[10];
    const float* vyb = (const float*)d_in[11];
    const float* Wih = (const float*)d_in[12];
    const float* Whh = (const float*)d_in[13];
    const float* bih = (const float*)d_in[14];
    const float* bhh = (const float*)d_in[15];
    float* out = (float*)d_out;
    const int N = Bsz * Psz;   // 262144

    // workspace: Uyh | W16 | bf16 states | f32 scratch | ench (guarded)
    char* p = (char*)d_ws;
    unsigned short* Uyh = (unsigned short*)p;  p += (size_t)Bsz * Tsz * Msz * 2;   // 64 MB
    unsigned short* W16 = (unsigned short*)p;  p += (size_t)3072 * 512 * 2;        // 3 MB
    unsigned short* dbh = (unsigned short*)p;  p += (size_t)2 * N * 2;             // 1 MB
    unsigned short* sbh = (unsigned short*)p;  p += (size_t)2 * N * 2;             // 1 MB
    float* dbuf = (float*)p;  p += (size_t)2 * N * 4;                              // 2 MB
    float* sbuf = (float*)p;  p += (size_t)2 * N * 4;                              // 2 MB
    float* x1g  = (float*)p;  p += (size_t)N * 4;                                  // 1 MB
    float* cb   = (float*)p;  p += (size_t)N * 4;                                  // 1 MB
    float* gacc = (float*)p;  p += (size_t)Bsz * 2048 * 4;                         // 4 MB
    float* ytl  = (float*)p;  p += (size_t)Bsz * 4;
    unsigned short* ench = (unsigned short*)p;
    const size_t need = (size_t)((char*)(ench + (size_t)Bsz * Tsz * Msz) - (char*)d_ws);
    const int useh = (ws_size >= need) ? 1 : 0;

    k_uy<<<dim3(Msz / 64, (Bsz * Tsz) / 64), 256, 0, stream>>>(enc, Udw, Uyh);
    if (useh)
        k_e2h<<<(Bsz * Tsz * Msz) / (256 * 8), 256, 0, stream>>>(enc, ench);
    k_w2b<<<(3072 * 512) / (256 * 8), 256, 0, stream>>>(Whh, Wdw, W16);
    k_zero<<<(N + 255) / 256, 256, 0, stream>>>(dbuf, sbuf, dbh, sbh, N);

    for (int t = 0; t < Tsz; ++t) {
        const int c = t & 1, n = c ^ 1;
        k_mm<<<dim3(40, 8), 256, 0, stream>>>(dbh + (size_t)c * N, sbh + (size_t)c * N,
                                              W16, Wdb, gacc, x1g);
        k_attn<<<Bsz, 512, 0, stream>>>(Uyh, ench, enc, x1g, vdw, wtw, wtb, yin,
                                        cb, ytl, t, useh);
        k_upd<<<N / 256, 256, 0, stream>>>(gacc, ytl, Wih, bih, bhh,
                                           sbuf + (size_t)c * N,
                                           sbuf + (size_t)n * N, dbuf + (size_t)n * N,
                                           sbh + (size_t)n * N, dbh + (size_t)n * N);
    }
    // after 128 steps live parity is 0
    k_final<<<Bsz, 256, 0, stream>>>(dbuf, cb, Wyw, Wyb, vyw, vyb, out);
}

// Round 12
// 7292.078 us; speedup vs baseline: 3.5985x; 1.0307x over previous
//
#include <hip/hip_runtime.h>
#include <hip/hip_bf16.h>

#define Bsz 512
#define Tsz 128
#define Msz 512
#define Psz 512

typedef __attribute__((ext_vector_type(8))) unsigned short ushort8v;
typedef __attribute__((ext_vector_type(8))) short short8v;
typedef __attribute__((ext_vector_type(4))) float floatx4;

__device__ __forceinline__ float h2f(unsigned short u) {
    union { unsigned short u; _Float16 h; } c; c.u = u; return (float)c.h;
}
__device__ __forceinline__ unsigned short f2h(float f) {
    union { unsigned short u; _Float16 h; } c; c.h = (_Float16)f; return c.u;
}
__device__ __forceinline__ unsigned short f2bf(float f) {
    union { float f; unsigned int i; } c; c.f = f;
    unsigned int u = c.i;
    unsigned int r = u + 0x7fffu + ((u >> 16) & 1u);
    return (unsigned short)(r >> 16);
}
__device__ __forceinline__ float fast_tanh(float x) {
    x = fminf(fmaxf(x, -15.f), 15.f);
    float e = __expf(2.f * x);
    return 1.f - 2.f / (e + 1.f);
}
__device__ __forceinline__ float fast_sig(float x) {
    x = fminf(fmaxf(x, -30.f), 30.f);
    return 1.f / (1.f + __expf(-x));
}

// ---------------- Uy = encoded @ U^T, output fp16 (validated r8/r10) ----------------
__global__ __launch_bounds__(256) void k_uy(const float* __restrict__ A,
                                            const float* __restrict__ U,
                                            unsigned short* __restrict__ C) {
    __shared__ float As[32][68];
    __shared__ float Us[32][68];
    const int tid = threadIdx.x;
    const int tx = tid & 15, ty = tid >> 4;
    const size_t r0 = (size_t)blockIdx.y * 64;
    const int n0 = blockIdx.x * 64;
    float acc[4][4] = {};
    for (int k0 = 0; k0 < 512; k0 += 32) {
#pragma unroll
        for (int i = 0; i < 2; ++i) {
            int f = tid + i * 256;
            int r = f >> 3;
            int kc = (f & 7) * 4;
            float4 v = *reinterpret_cast<const float4*>(&A[(r0 + r) * 512 + k0 + kc]);
            As[kc + 0][r] = v.x; As[kc + 1][r] = v.y; As[kc + 2][r] = v.z; As[kc + 3][r] = v.w;
            float4 w = *reinterpret_cast<const float4*>(&U[(size_t)(n0 + r) * 512 + k0 + kc]);
            Us[kc + 0][r] = w.x; Us[kc + 1][r] = w.y; Us[kc + 2][r] = w.z; Us[kc + 3][r] = w.w;
        }
        __syncthreads();
#pragma unroll
        for (int k = 0; k < 32; ++k) {
            float4 a = *reinterpret_cast<const float4*>(&As[k][ty * 4]);
            float4 b = *reinterpret_cast<const float4*>(&Us[k][tx * 4]);
            float av[4] = {a.x, a.y, a.z, a.w};
            float bv[4] = {b.x, b.y, b.z, b.w};
#pragma unroll
            for (int i = 0; i < 4; ++i)
#pragma unroll
                for (int j = 0; j < 4; ++j)
                    acc[i][j] = fmaf(av[i], bv[j], acc[i][j]);
        }
        __syncthreads();
    }
#pragma unroll
    for (int i = 0; i < 4; ++i) {
        size_t row = r0 + ty * 4 + i;
        ushort4 o;
        o.x = f2h(acc[i][0]); o.y = f2h(acc[i][1]);
        o.z = f2h(acc[i][2]); o.w = f2h(acc[i][3]);
        *reinterpret_cast<ushort4*>(&C[row * 512 + n0 + tx * 4]) = o;
    }
}

// ---------------- enc f32 -> fp16 copy (validated r8/r10) ----------------
__global__ __launch_bounds__(256) void k_e2h(const float* __restrict__ e,
                                             unsigned short* __restrict__ o) {
    size_t i = ((size_t)blockIdx.x * 256 + threadIdx.x) * 8;
    float4 a = *reinterpret_cast<const float4*>(e + i);
    float4 b = *reinterpret_cast<const float4*>(e + i + 4);
    ushort8v r;
    r[0] = f2h(a.x); r[1] = f2h(a.y); r[2] = f2h(a.z); r[3] = f2h(a.w);
    r[4] = f2h(b.x); r[5] = f2h(b.y); r[6] = f2h(b.z); r[7] = f2h(b.w);
    *reinterpret_cast<ushort8v*>(o + i) = r;
}

// ---------------- weights -> bf16: W16 = [Whh(2048) | Wd[:,:512] | Wd[:,512:]] (r10) ----------------
__global__ __launch_bounds__(256) void k_w2b(const float* __restrict__ Whh,
                                             const float* __restrict__ Wdw,
                                             unsigned short* __restrict__ W16) {
    size_t o = ((size_t)blockIdx.x * 256 + threadIdx.x) * 8;   // 3072*512 elems total
    int row = (int)(o >> 9), k = (int)(o & 511);
    const float* src;
    if (row < 2048)      src = &Whh[(size_t)row * 512 + k];
    else if (row < 2560) src = &Wdw[(size_t)(row - 2048) * 1024 + k];
    else                 src = &Wdw[(size_t)(row - 2560) * 1024 + 512 + k];
    float4 a = *reinterpret_cast<const float4*>(src);
    float4 b = *reinterpret_cast<const float4*>(src + 4);
    ushort8v r;
    r[0] = f2bf(a.x); r[1] = f2bf(a.y); r[2] = f2bf(a.z); r[3] = f2bf(a.w);
    r[4] = f2bf(b.x); r[5] = f2bf(b.y); r[6] = f2bf(b.z); r[7] = f2bf(b.w);
    *reinterpret_cast<ushort8v*>(W16 + o) = r;
}

// ---------------- zero-init states (f32 + bf16) ----------------
__global__ void k_zero(float* a, float* b, unsigned short* ah, unsigned short* bh, int n) {
    int i = blockIdx.x * blockDim.x + threadIdx.x;
    if (i < n) { a[i] = 0.f; b[i] = 0.f; ah[i] = 0; bh[i] = 0; }
}

// ---------------- K1: MFMA GEMM — gacc = d@Whh^T ; x1 = d@WdA^T + s@WdB^T + bias (r10) ----------------
__global__ __launch_bounds__(256) void k_mm(const unsigned short* __restrict__ dbh,
                                            const unsigned short* __restrict__ sbh,
                                            const unsigned short* __restrict__ W16,
                                            const float* __restrict__ Wdb,
                                            float* __restrict__ gacc,
                                            float* __restrict__ x1g) {
    __shared__ unsigned short As[64][48];   // pitch 96 B (16B-aligned for ds_read_b128)
    __shared__ unsigned short Ws[64][48];
    const int tid = threadIdx.x;
    const int lane = tid & 63, w = tid >> 6;
    const int rbw = (w >> 1) * 32, cbw = (w & 1) * 32;
    const int b0 = blockIdx.y * 64;
    const int n0 = blockIdx.x * 64;                      // [0,2048) gates, [2048,2560) x1
    const bool isx1 = (n0 >= 2048);
    const int l15 = lane & 15, kq = (lane >> 4) * 8;
    floatx4 acc00 = {}, acc01 = {}, acc10 = {}, acc11 = {};

    const int npass = isx1 ? 2 : 1;
    for (int pass = 0; pass < npass; ++pass) {
        const unsigned short* Ab = (pass == 0) ? dbh : sbh;
        const unsigned short* Wb = W16 + (size_t)(pass == 0 ? n0 : n0 + 512) * 512;
        for (int k0 = 0; k0 < 512; k0 += 32) {
            {
                const int r = tid >> 2, kc = (tid & 3) * 8;
                *reinterpret_cast<ushort8v*>(&As[r][kc]) =
                    *reinterpret_cast<const ushort8v*>(&Ab[(size_t)(b0 + r) * 512 + k0 + kc]);
                *reinterpret_cast<ushort8v*>(&Ws[r][kc]) =
                    *reinterpret_cast<const ushort8v*>(&Wb[(size_t)r * 512 + k0 + kc]);
            }
            __syncthreads();
            short8v a0 = *reinterpret_cast<const short8v*>(&As[rbw + l15][kq]);
            short8v a1 = *reinterpret_cast<const short8v*>(&As[rbw + 16 + l15][kq]);
            short8v q0 = *reinterpret_cast<const short8v*>(&Ws[cbw + l15][kq]);
            short8v q1 = *reinterpret_cast<const short8v*>(&Ws[cbw + 16 + l15][kq]);
            acc00 = __builtin_amdgcn_mfma_f32_16x16x32_bf16(a0, q0, acc00, 0, 0, 0);
            acc01 = __builtin_amdgcn_mfma_f32_16x16x32_bf16(a0, q1, acc01, 0, 0, 0);
            acc10 = __builtin_amdgcn_mfma_f32_16x16x32_bf16(a1, q0, acc10, 0, 0, 0);
            acc11 = __builtin_amdgcn_mfma_f32_16x16x32_bf16(a1, q1, acc11, 0, 0, 0);
            __syncthreads();
        }
    }
    // C/D layout (verified): col = lane&15, row = (lane>>4)*4 + reg
    const int rB = rbw + (lane >> 4) * 4;
#pragma unroll
    for (int fr = 0; fr < 2; ++fr)
#pragma unroll
        for (int fc = 0; fc < 2; ++fc) {
            const floatx4 av = fr ? (fc ? acc11 : acc10) : (fc ? acc01 : acc00);
            const int col = cbw + fc * 16 + l15;
#pragma unroll
            for (int i = 0; i < 4; ++i) {
                const int row = b0 + rB + fr * 16 + i;
                if (!isx1) {
                    gacc[(size_t)row * 2048 + n0 + col] = av[i];
                } else {
                    const int m = (n0 - 2048) + col;
                    x1g[(size_t)row * 512 + m] = av[i] + Wdb[m];
                }
            }
        }
}

// ---------------- K2: fused attention + LSTM update per b ----------------
__global__ __launch_bounds__(512) void k_attn2(const unsigned short* __restrict__ Uyh,
                                               const unsigned short* __restrict__ ench,
                                               const float* __restrict__ encf,
                                               const float* __restrict__ x1g,
                                               const float* __restrict__ vd,
                                               const float* __restrict__ wt,
                                               const float* __restrict__ wtb,
                                               const float* __restrict__ yin,
                                               const float* __restrict__ gacc,
                                               const float* __restrict__ Wih,
                                               const float* __restrict__ bih,
                                               const float* __restrict__ bhh,
                                               const float* __restrict__ scur,
                                               float* __restrict__ snxt,
                                               float* __restrict__ dnxt,
                                               unsigned short* __restrict__ snh,
                                               unsigned short* __restrict__ dnh,
                                               float* __restrict__ cout,
                                               int tstep, int useh) {
    __shared__ float x1_s[512];
    __shared__ float l_s[128];
    __shared__ float pacc[8][512];
    __shared__ float sred[8];
    __shared__ float y_bc;
    const int tid = threadIdx.x, b = blockIdx.x;
    const int w = tid >> 6, lane = tid & 63;
    x1_s[tid] = x1g[(size_t)b * 512 + tid];
    __syncthreads();
    // logits (validated r7/r10 phase)
    {
        const int mb = lane * 8;
        float4 xa = *reinterpret_cast<const float4*>(&x1_s[mb]);
        float4 xb = *reinterpret_cast<const float4*>(&x1_s[mb + 4]);
        float4 va = *reinterpret_cast<const float4*>(&vd[mb]);
        float4 vb = *reinterpret_cast<const float4*>(&vd[mb + 4]);
        const unsigned short* ubase = Uyh + (size_t)b * 128 * 512 + mb;
#pragma unroll 2
        for (int tt = 0; tt < 16; ++tt) {
            const int t = w * 16 + tt;
            ushort8v u = *reinterpret_cast<const ushort8v*>(ubase + (size_t)t * 512);
            float s;
            s  = fast_tanh(h2f(u[0]) + xa.x) * va.x;
            s += fast_tanh(h2f(u[1]) + xa.y) * va.y;
            s += fast_tanh(h2f(u[2]) + xa.z) * va.z;
            s += fast_tanh(h2f(u[3]) + xa.w) * va.w;
            s += fast_tanh(h2f(u[4]) + xb.x) * vb.x;
            s += fast_tanh(h2f(u[5]) + xb.y) * vb.y;
            s += fast_tanh(h2f(u[6]) + xb.z) * vb.z;
            s += fast_tanh(h2f(u[7]) + xb.w) * vb.w;
#pragma unroll
            for (int off = 32; off; off >>= 1) s += __shfl_xor(s, off);
            if (lane == 0) l_s[t] = s;
        }
    }
    __syncthreads();
    // softmax over 128 (validated r8/r10)
    if (tid < 64) {
        float v0 = l_s[tid], v1 = l_s[tid + 64];
        float mx = fmaxf(v0, v1);
#pragma unroll
        for (int off = 32; off; off >>= 1) mx = fmaxf(mx, __shfl_xor(mx, off));
        float e0 = __expf(v0 - mx), e1 = __expf(v1 - mx);
        float sm = e0 + e1;
#pragma unroll
        for (int off = 32; off; off >>= 1) sm += __shfl_xor(sm, off);
        float inv = 1.f / sm;
        l_s[tid] = e0 * inv; l_s[tid + 64] = e1 * inv;
    }
    __syncthreads();
    // c_t (validated r8/r10)
    float a0 = 0.f, a1 = 0.f, a2 = 0.f, a3 = 0.f, a4 = 0.f, a5 = 0.f, a6 = 0.f, a7 = 0.f;
    if (useh) {
        const unsigned short* eb = ench + (size_t)b * (Tsz * Msz) + lane * 8;
#pragma unroll
        for (int tt = 0; tt < 16; ++tt) {
            const int t = tt * 8 + w;
            ushort8v uu = *reinterpret_cast<const ushort8v*>(eb + (size_t)t * 512);
            const float bt = l_s[t];
            a0 = fmaf(bt, h2f(uu[0]), a0); a1 = fmaf(bt, h2f(uu[1]), a1);
            a2 = fmaf(bt, h2f(uu[2]), a2); a3 = fmaf(bt, h2f(uu[3]), a3);
            a4 = fmaf(bt, h2f(uu[4]), a4); a5 = fmaf(bt, h2f(uu[5]), a5);
            a6 = fmaf(bt, h2f(uu[6]), a6); a7 = fmaf(bt, h2f(uu[7]), a7);
        }
    } else {
        const float* eb = encf + (size_t)b * (Tsz * Msz) + lane * 8;
#pragma unroll
        for (int tt = 0; tt < 16; ++tt) {
            const int t = tt * 8 + w;
            float4 e0 = *reinterpret_cast<const float4*>(eb + (size_t)t * 512);
            float4 e1 = *reinterpret_cast<const float4*>(eb + (size_t)t * 512 + 4);
            const float bt = l_s[t];
            a0 = fmaf(bt, e0.x, a0); a1 = fmaf(bt, e0.y, a1);
            a2 = fmaf(bt, e0.z, a2); a3 = fmaf(bt, e0.w, a3);
            a4 = fmaf(bt, e1.x, a4); a5 = fmaf(bt, e1.y, a5);
            a6 = fmaf(bt, e1.z, a6); a7 = fmaf(bt, e1.w, a7);
        }
    }
    float* pr = &pacc[w][lane * 8];
    *reinterpret_cast<float4*>(pr)     = make_float4(a0, a1, a2, a3);
    *reinterpret_cast<float4*>(pr + 4) = make_float4(a4, a5, a6, a7);
    __syncthreads();
    float c = pacc[0][tid];
#pragma unroll
    for (int ww = 1; ww < 8; ++ww) c += pacc[ww][tid];
    cout[(size_t)b * 512 + tid] = c;
    float part = c * wt[tid];
#pragma unroll
    for (int off = 32; off; off >>= 1) part += __shfl_xor(part, off);
    if (lane == 0) sred[w] = part;
    __syncthreads();
    if (tid == 0) {
        float tot = sred[0] + sred[1] + sred[2] + sred[3] +
                    sred[4] + sred[5] + sred[6] + sred[7];
        y_bc = tot + yin[(size_t)b * 128 + tstep] * wt[512] + wtb[0];
    }
    __syncthreads();
    // fused LSTM update for row b, p = tid (was k_upd, validated r7/r10 logic)
    {
        const float yt = y_bc;
        const int p = tid;
        const int e = b * 512 + p;
        const float* ga = gacc + (size_t)b * 2048;
        float gi = ga[p]        + yt * Wih[p]        + bih[p]        + bhh[p];
        float gf = ga[512 + p]  + yt * Wih[512 + p]  + bih[512 + p]  + bhh[512 + p];
        float gg = ga[1024 + p] + yt * Wih[1024 + p] + bih[1024 + p] + bhh[1024 + p];
        float go = ga[1536 + p] + yt * Wih[1536 + p] + bih[1536 + p] + bhh[1536 + p];
        float sv = fast_sig(gf) * scur[e] + fast_sig(gi) * fast_tanh(gg);
        float dv = fast_sig(go) * fast_tanh(sv);
        snxt[e] = sv; dnxt[e] = dv;
        snh[e] = f2bf(sv); dnh[e] = f2bf(dv);
    }
}

// ---------------- final projection (validated r3/r10) ----------------
__global__ __launch_bounds__(256) void k_final(const float* __restrict__ dfin,
                                               const float* __restrict__ cfin,
                                               const float* __restrict__ Wy,
                                               const float* __restrict__ Wyb,
                                               const float* __restrict__ vy,
                                               const float* __restrict__ vyb,
                                               float* __restrict__ out) {
    __shared__ float hc[1024];
    __shared__ float sred[8];
    const int tid = threadIdx.x, b = blockIdx.x;
    hc[tid] = dfin[(size_t)b * 512 + tid];
    hc[256 + tid] = dfin[(size_t)b * 512 + 256 + tid];
    hc[512 + tid] = cfin[(size_t)b * 512 + tid];
    hc[768 + tid] = cfin[(size_t)b * 512 + 256 + tid];
    __syncthreads();
    float part = 0.f;
#pragma unroll
    for (int pi = 0; pi < 2; ++pi) {
        int p = tid + pi * 256;
        float acc = Wyb[p];
        const float* wr = Wy + (size_t)p * 1024;
#pragma unroll 4
        for (int k = 0; k < 1024; k += 4) {
            float4 w = *reinterpret_cast<const float4*>(&wr[k]);
            acc = fmaf(hc[k], w.x, acc);
            acc = fmaf(hc[k + 1], w.y, acc);
            acc = fmaf(hc[k + 2], w.z, acc);
            acc = fmaf(hc[k + 3], w.w, acc);
        }
        part += acc * vy[p];
    }
#pragma unroll
    for (int off = 32; off; off >>= 1) part += __shfl_xor(part, off);
    const int lane = tid & 63, wid = tid >> 6;
    if (lane == 0) sred[wid] = part;
    __syncthreads();
    if (tid == 0) out[b] = sred[0] + sred[1] + sred[2] + sred[3] + vyb[0];
}

extern "C" void kernel_launch(void* const* d_in, const int* in_sizes, int n_in,
                              void* d_out, int out_size, void* d_ws, size_t ws_size,
                              hipStream_t stream) {
    const float* enc = (const float*)d_in[0];
    const float* yin = (const float*)d_in[1];
    const float* Wdw = (const float*)d_in[2];
    const float* Wdb = (const float*)d_in[3];
    const float* Udw = (const float*)d_in[4];
    const float* vdw = (const float*)d_in[5];
    const float* wtw = (const float*)d_in[6];
    const float* wtb = (const float*)d_in[7];
    const float* Wyw = (const float*)d_in[8];
    const float* Wyb = (const float*)d_in[9];
    const float* vyw = (const float*)d_in[10];
    const float* vyb = (const float*)d_in[11];
    const float* Wih = (const float*)d_in[12];
    const float* Whh = (const float*)d_in[13];
    const float* bih = (const float*)d_in[14];
    const float* bhh = (const float*)d_in[15];
    float* out = (float*)d_out;
    const int N = Bsz * Psz;   // 262144

    // workspace: Uyh | W16 | bf16 states | f32 scratch | ench (guarded)
    char* p = (char*)d_ws;
    unsigned short* Uyh = (unsigned short*)p;  p += (size_t)Bsz * Tsz * Msz * 2;   // 64 MB
    unsigned short* W16 = (unsigned short*)p;  p += (size_t)3072 * 512 * 2;        // 3 MB
    unsigned short* dbh = (unsigned short*)p;  p += (size_t)2 * N * 2;             // 1 MB
    unsigned short* sbh = (unsigned short*)p;  p += (size_t)2 * N * 2;             // 1 MB
    float* dbuf = (float*)p;  p += (size_t)2 * N * 4;                              // 2 MB
    float* sbuf = (float*)p;  p += (size_t)2 * N * 4;                              // 2 MB
    float* x1g  = (float*)p;  p += (size_t)N * 4;                                  // 1 MB
    float* cb   = (float*)p;  p += (size_t)N * 4;                                  // 1 MB
    float* gacc = (float*)p;  p += (size_t)Bsz * 2048 * 4;                         // 4 MB
    unsigned short* ench = (unsigned short*)p;
    const size_t need = (size_t)((char*)(ench + (size_t)Bsz * Tsz * Msz) - (char*)d_ws);
    const int useh = (ws_size >= need) ? 1 : 0;

    k_uy<<<dim3(Msz / 64, (Bsz * Tsz) / 64), 256, 0, stream>>>(enc, Udw, Uyh);
    if (useh)
        k_e2h<<<(Bsz * Tsz * Msz) / (256 * 8), 256, 0, stream>>>(enc, ench);
    k_w2b<<<(3072 * 512) / (256 * 8), 256, 0, stream>>>(Whh, Wdw, W16);
    k_zero<<<(N + 255) / 256, 256, 0, stream>>>(dbuf, sbuf, dbh, sbh, N);

    for (int t = 0; t < Tsz; ++t) {
        const int c = t & 1, n = c ^ 1;
        k_mm<<<dim3(40, 8), 256, 0, stream>>>(dbh + (size_t)c * N, sbh + (size_t)c * N,
                                              W16, Wdb, gacc, x1g);
        k_attn2<<<Bsz, 512, 0, stream>>>(Uyh, ench, enc, x1g, vdw, wtw, wtb, yin,
                                         gacc, Wih, bih, bhh,
                                         sbuf + (size_t)c * N,
                                         sbuf + (size_t)n * N, dbuf + (size_t)n * N,
                                         sbh + (size_t)n * N, dbh + (size_t)n * N,
                                         cb, t, useh);
    }
    // after 128 steps live parity is 0
    k_final<<<Bsz, 256, 0, stream>>>(dbuf, cb, Wyw, Wyb, vyw, vyb, out);
}

// Round 13
// 6440.698 us; speedup vs baseline: 4.0742x; 1.1322x over previous
//
#include <hip/hip_runtime.h>
#include <hip/hip_bf16.h>

#define Bsz 512
#define Tsz 128
#define Msz 512
#define Psz 512

typedef __attribute__((ext_vector_type(8))) unsigned short ushort8v;
typedef __attribute__((ext_vector_type(8))) short short8v;
typedef __attribute__((ext_vector_type(4))) float floatx4;

__device__ __forceinline__ float h2f(unsigned short u) {
    union { unsigned short u; _Float16 h; } c; c.u = u; return (float)c.h;
}
__device__ __forceinline__ unsigned short f2h(float f) {
    union { unsigned short u; _Float16 h; } c; c.h = (_Float16)f; return c.u;
}
__device__ __forceinline__ unsigned short f2bf(float f) {
    union { float f; unsigned int i; } c; c.f = f;
    unsigned int u = c.i;
    unsigned int r = u + 0x7fffu + ((u >> 16) & 1u);
    return (unsigned short)(r >> 16);
}
__device__ __forceinline__ float fast_tanh(float x) {
    x = fminf(fmaxf(x, -15.f), 15.f);
    float e = __expf(2.f * x);
    return 1.f - 2.f / (e + 1.f);
}
__device__ __forceinline__ float fast_sig(float x) {
    x = fminf(fmaxf(x, -30.f), 30.f);
    return 1.f / (1.f + __expf(-x));
}

// ---------------- Uy = encoded @ U^T, output fp16 (validated r8/r10/r12) ----------------
__global__ __launch_bounds__(256) void k_uy(const float* __restrict__ A,
                                            const float* __restrict__ U,
                                            unsigned short* __restrict__ C) {
    __shared__ float As[32][68];
    __shared__ float Us[32][68];
    const int tid = threadIdx.x;
    const int tx = tid & 15, ty = tid >> 4;
    const size_t r0 = (size_t)blockIdx.y * 64;
    const int n0 = blockIdx.x * 64;
    float acc[4][4] = {};
    for (int k0 = 0; k0 < 512; k0 += 32) {
#pragma unroll
        for (int i = 0; i < 2; ++i) {
            int f = tid + i * 256;
            int r = f >> 3;
            int kc = (f & 7) * 4;
            float4 v = *reinterpret_cast<const float4*>(&A[(r0 + r) * 512 + k0 + kc]);
            As[kc + 0][r] = v.x; As[kc + 1][r] = v.y; As[kc + 2][r] = v.z; As[kc + 3][r] = v.w;
            float4 w = *reinterpret_cast<const float4*>(&U[(size_t)(n0 + r) * 512 + k0 + kc]);
            Us[kc + 0][r] = w.x; Us[kc + 1][r] = w.y; Us[kc + 2][r] = w.z; Us[kc + 3][r] = w.w;
        }
        __syncthreads();
#pragma unroll
        for (int k = 0; k < 32; ++k) {
            float4 a = *reinterpret_cast<const float4*>(&As[k][ty * 4]);
            float4 b = *reinterpret_cast<const float4*>(&Us[k][tx * 4]);
            float av[4] = {a.x, a.y, a.z, a.w};
            float bv[4] = {b.x, b.y, b.z, b.w};
#pragma unroll
            for (int i = 0; i < 4; ++i)
#pragma unroll
                for (int j = 0; j < 4; ++j)
                    acc[i][j] = fmaf(av[i], bv[j], acc[i][j]);
        }
        __syncthreads();
    }
#pragma unroll
    for (int i = 0; i < 4; ++i) {
        size_t row = r0 + ty * 4 + i;
        ushort4 o;
        o.x = f2h(acc[i][0]); o.y = f2h(acc[i][1]);
        o.z = f2h(acc[i][2]); o.w = f2h(acc[i][3]);
        *reinterpret_cast<ushort4*>(&C[row * 512 + n0 + tx * 4]) = o;
    }
}

// ---------------- ewt[b,t] = enc[b,t,:] . wt[:512]  (one wave per pair) ----------------
__global__ __launch_bounds__(256) void k_ewt(const float* __restrict__ enc,
                                             const float* __restrict__ wt,
                                             float* __restrict__ ewt) {
    const int lane = threadIdx.x & 63;
    const int pair = blockIdx.x * 4 + (threadIdx.x >> 6);   // b*128 + t
    const float* e = enc + (size_t)pair * 512 + lane * 8;
    float4 a = *reinterpret_cast<const float4*>(e);
    float4 b = *reinterpret_cast<const float4*>(e + 4);
    const float* wp = wt + lane * 8;
    float4 w0 = *reinterpret_cast<const float4*>(wp);
    float4 w1 = *reinterpret_cast<const float4*>(wp + 4);
    float s = a.x * w0.x + a.y * w0.y + a.z * w0.z + a.w * w0.w +
              b.x * w1.x + b.y * w1.y + b.z * w1.z + b.w * w1.w;
#pragma unroll
    for (int off = 32; off; off >>= 1) s += __shfl_xor(s, off);
    if (lane == 0) ewt[pair] = s;
}

// ---------------- weights -> bf16: W16 = [Whh(2048) | Wd[:,:512] | Wd[:,512:]] (r10) ----------------
__global__ __launch_bounds__(256) void k_w2b(const float* __restrict__ Whh,
                                             const float* __restrict__ Wdw,
                                             unsigned short* __restrict__ W16) {
    size_t o = ((size_t)blockIdx.x * 256 + threadIdx.x) * 8;   // 3072*512 elems total
    int row = (int)(o >> 9), k = (int)(o & 511);
    const float* src;
    if (row < 2048)      src = &Whh[(size_t)row * 512 + k];
    else if (row < 2560) src = &Wdw[(size_t)(row - 2048) * 1024 + k];
    else                 src = &Wdw[(size_t)(row - 2560) * 1024 + 512 + k];
    float4 a = *reinterpret_cast<const float4*>(src);
    float4 b = *reinterpret_cast<const float4*>(src + 4);
    ushort8v r;
    r[0] = f2bf(a.x); r[1] = f2bf(a.y); r[2] = f2bf(a.z); r[3] = f2bf(a.w);
    r[4] = f2bf(b.x); r[5] = f2bf(b.y); r[6] = f2bf(b.z); r[7] = f2bf(b.w);
    *reinterpret_cast<ushort8v*>(W16 + o) = r;
}

// ---------------- zero-init states (f32 + bf16) ----------------
__global__ void k_zero(float* a, float* b, unsigned short* ah, unsigned short* bh, int n) {
    int i = blockIdx.x * blockDim.x + threadIdx.x;
    if (i < n) { a[i] = 0.f; b[i] = 0.f; ah[i] = 0; bh[i] = 0; }
}

// ---------------- K1: MFMA GEMM — gacc = d@Whh^T ; x1 = d@WdA^T + s@WdB^T + bias (r10/r12) -------
__global__ __launch_bounds__(256) void k_mm(const unsigned short* __restrict__ dbh,
                                            const unsigned short* __restrict__ sbh,
                                            const unsigned short* __restrict__ W16,
                                            const float* __restrict__ Wdb,
                                            float* __restrict__ gacc,
                                            float* __restrict__ x1g) {
    __shared__ unsigned short As[64][48];   // pitch 96 B (16B-aligned for ds_read_b128)
    __shared__ unsigned short Ws[64][48];
    const int tid = threadIdx.x;
    const int lane = tid & 63, w = tid >> 6;
    const int rbw = (w >> 1) * 32, cbw = (w & 1) * 32;
    const int b0 = blockIdx.y * 64;
    const int n0 = blockIdx.x * 64;                      // [0,2048) gates, [2048,2560) x1
    const bool isx1 = (n0 >= 2048);
    const int l15 = lane & 15, kq = (lane >> 4) * 8;
    floatx4 acc00 = {}, acc01 = {}, acc10 = {}, acc11 = {};

    const int npass = isx1 ? 2 : 1;
    for (int pass = 0; pass < npass; ++pass) {
        const unsigned short* Ab = (pass == 0) ? dbh : sbh;
        const unsigned short* Wb = W16 + (size_t)(pass == 0 ? n0 : n0 + 512) * 512;
        for (int k0 = 0; k0 < 512; k0 += 32) {
            {
                const int r = tid >> 2, kc = (tid & 3) * 8;
                *reinterpret_cast<ushort8v*>(&As[r][kc]) =
                    *reinterpret_cast<const ushort8v*>(&Ab[(size_t)(b0 + r) * 512 + k0 + kc]);
                *reinterpret_cast<ushort8v*>(&Ws[r][kc]) =
                    *reinterpret_cast<const ushort8v*>(&Wb[(size_t)r * 512 + k0 + kc]);
            }
            __syncthreads();
            short8v a0 = *reinterpret_cast<const short8v*>(&As[rbw + l15][kq]);
            short8v a1 = *reinterpret_cast<const short8v*>(&As[rbw + 16 + l15][kq]);
            short8v q0 = *reinterpret_cast<const short8v*>(&Ws[cbw + l15][kq]);
            short8v q1 = *reinterpret_cast<const short8v*>(&Ws[cbw + 16 + l15][kq]);
            acc00 = __builtin_amdgcn_mfma_f32_16x16x32_bf16(a0, q0, acc00, 0, 0, 0);
            acc01 = __builtin_amdgcn_mfma_f32_16x16x32_bf16(a0, q1, acc01, 0, 0, 0);
            acc10 = __builtin_amdgcn_mfma_f32_16x16x32_bf16(a1, q0, acc10, 0, 0, 0);
            acc11 = __builtin_amdgcn_mfma_f32_16x16x32_bf16(a1, q1, acc11, 0, 0, 0);
            __syncthreads();
        }
    }
    // C/D layout (verified): col = lane&15, row = (lane>>4)*4 + reg
    const int rB = rbw + (lane >> 4) * 4;
#pragma unroll
    for (int fr = 0; fr < 2; ++fr)
#pragma unroll
        for (int fc = 0; fc < 2; ++fc) {
            const floatx4 av = fr ? (fc ? acc11 : acc10) : (fc ? acc01 : acc00);
            const int col = cbw + fc * 16 + l15;
#pragma unroll
            for (int i = 0; i < 4; ++i) {
                const int row = b0 + rB + fr * 16 + i;
                if (!isx1) {
                    gacc[(size_t)row * 2048 + n0 + col] = av[i];
                } else {
                    const int m = (n0 - 2048) + col;
                    x1g[(size_t)row * 512 + m] = av[i] + Wdb[m];
                }
            }
        }
}

// ---------------- K2: attention (logits+softmax+y_tilda via ewt) + LSTM update per b ------------
// c_T vector is only needed at the LAST step (feeds k_final); y_tilda uses
// wt.c_t = beta . ewt[b,:] with ewt precomputed (exact identity).
__global__ __launch_bounds__(512) void k_attn3(const unsigned short* __restrict__ Uyh,
                                               const float* __restrict__ encf,
                                               const float* __restrict__ ewt,
                                               const float* __restrict__ x1g,
                                               const float* __restrict__ vd,
                                               const float* __restrict__ wt,
                                               const float* __restrict__ wtb,
                                               const float* __restrict__ yin,
                                               const float* __restrict__ gacc,
                                               const float* __restrict__ Wih,
                                               const float* __restrict__ bih,
                                               const float* __restrict__ bhh,
                                               const float* __restrict__ scur,
                                               float* __restrict__ snxt,
                                               float* __restrict__ dnxt,
                                               unsigned short* __restrict__ snh,
                                               unsigned short* __restrict__ dnh,
                                               float* __restrict__ cout,
                                               int tstep) {
    __shared__ float x1_s[512];
    __shared__ float l_s[128];
    __shared__ float pacc[8][512];
    __shared__ float y_bc;
    const int tid = threadIdx.x, b = blockIdx.x;
    const int w = tid >> 6, lane = tid & 63;
    x1_s[tid] = x1g[(size_t)b * 512 + tid];
    __syncthreads();
    // logits (validated r7/r10/r12 phase)
    {
        const int mb = lane * 8;
        float4 xa = *reinterpret_cast<const float4*>(&x1_s[mb]);
        float4 xb = *reinterpret_cast<const float4*>(&x1_s[mb + 4]);
        float4 va = *reinterpret_cast<const float4*>(&vd[mb]);
        float4 vb = *reinterpret_cast<const float4*>(&vd[mb + 4]);
        const unsigned short* ubase = Uyh + (size_t)b * 128 * 512 + mb;
#pragma unroll 2
        for (int tt = 0; tt < 16; ++tt) {
            const int t = w * 16 + tt;
            ushort8v u = *reinterpret_cast<const ushort8v*>(ubase + (size_t)t * 512);
            float s;
            s  = fast_tanh(h2f(u[0]) + xa.x) * va.x;
            s += fast_tanh(h2f(u[1]) + xa.y) * va.y;
            s += fast_tanh(h2f(u[2]) + xa.z) * va.z;
            s += fast_tanh(h2f(u[3]) + xa.w) * va.w;
            s += fast_tanh(h2f(u[4]) + xb.x) * vb.x;
            s += fast_tanh(h2f(u[5]) + xb.y) * vb.y;
            s += fast_tanh(h2f(u[6]) + xb.z) * vb.z;
            s += fast_tanh(h2f(u[7]) + xb.w) * vb.w;
#pragma unroll
            for (int off = 32; off; off >>= 1) s += __shfl_xor(s, off);
            if (lane == 0) l_s[t] = s;
        }
    }
    __syncthreads();
    // softmax over 128 (validated r8/r10/r12)
    if (tid < 64) {
        float v0 = l_s[tid], v1 = l_s[tid + 64];
        float mx = fmaxf(v0, v1);
#pragma unroll
        for (int off = 32; off; off >>= 1) mx = fmaxf(mx, __shfl_xor(mx, off));
        float e0 = __expf(v0 - mx), e1 = __expf(v1 - mx);
        float sm = e0 + e1;
#pragma unroll
        for (int off = 32; off; off >>= 1) sm += __shfl_xor(sm, off);
        float inv = 1.f / sm;
        l_s[tid] = e0 * inv; l_s[tid + 64] = e1 * inv;
    }
    __syncthreads();
    // y_tilda = beta . ewt[b,:] + y*wt[512] + b   (wave 0 only; exact identity)
    if (w == 0) {
        const float* er = ewt + b * 128;
        float pp = l_s[lane] * er[lane] + l_s[lane + 64] * er[lane + 64];
#pragma unroll
        for (int off = 32; off; off >>= 1) pp += __shfl_xor(pp, off);
        if (lane == 0)
            y_bc = pp + yin[(size_t)b * 128 + tstep] * wt[512] + wtb[0];
    }
    // c_T only at the final step (f32 enc — one-time 134 MB stream)
    if (tstep == Tsz - 1) {
        const float* eb = encf + (size_t)b * (Tsz * Msz) + lane * 8;
        float a0 = 0.f, a1 = 0.f, a2 = 0.f, a3 = 0.f, a4 = 0.f, a5 = 0.f, a6 = 0.f, a7 = 0.f;
#pragma unroll
        for (int tt = 0; tt < 16; ++tt) {
            const int t = tt * 8 + w;
            float4 e0 = *reinterpret_cast<const float4*>(eb + (size_t)t * 512);
            float4 e1 = *reinterpret_cast<const float4*>(eb + (size_t)t * 512 + 4);
            const float bt = l_s[t];
            a0 = fmaf(bt, e0.x, a0); a1 = fmaf(bt, e0.y, a1);
            a2 = fmaf(bt, e0.z, a2); a3 = fmaf(bt, e0.w, a3);
            a4 = fmaf(bt, e1.x, a4); a5 = fmaf(bt, e1.y, a5);
            a6 = fmaf(bt, e1.z, a6); a7 = fmaf(bt, e1.w, a7);
        }
        float* pr = &pacc[w][lane * 8];
        *reinterpret_cast<float4*>(pr)     = make_float4(a0, a1, a2, a3);
        *reinterpret_cast<float4*>(pr + 4) = make_float4(a4, a5, a6, a7);
    }
    __syncthreads();
    if (tstep == Tsz - 1) {
        float c = pacc[0][tid];
#pragma unroll
        for (int ww = 1; ww < 8; ++ww) c += pacc[ww][tid];
        cout[(size_t)b * 512 + tid] = c;
    }
    // fused LSTM update for row b, p = tid (validated r7/r10/r12 logic)
    {
        const float yt = y_bc;
        const int p = tid;
        const int e = b * 512 + p;
        const float* ga = gacc + (size_t)b * 2048;
        float gi = ga[p]        + yt * Wih[p]        + bih[p]        + bhh[p];
        float gf = ga[512 + p]  + yt * Wih[512 + p]  + bih[512 + p]  + bhh[512 + p];
        float gg = ga[1024 + p] + yt * Wih[1024 + p] + bih[1024 + p] + bhh[1024 + p];
        float go = ga[1536 + p] + yt * Wih[1536 + p] + bih[1536 + p] + bhh[1536 + p];
        float sv = fast_sig(gf) * scur[e] + fast_sig(gi) * fast_tanh(gg);
        float dv = fast_sig(go) * fast_tanh(sv);
        snxt[e] = sv; dnxt[e] = dv;
        snh[e] = f2bf(sv); dnh[e] = f2bf(dv);
    }
}

// ---------------- final projection (validated r3/r10/r12) ----------------
__global__ __launch_bounds__(256) void k_final(const float* __restrict__ dfin,
                                               const float* __restrict__ cfin,
                                               const float* __restrict__ Wy,
                                               const float* __restrict__ Wyb,
                                               const float* __restrict__ vy,
                                               const float* __restrict__ vyb,
                                               float* __restrict__ out) {
    __shared__ float hc[1024];
    __shared__ float sred[8];
    const int tid = threadIdx.x, b = blockIdx.x;
    hc[tid] = dfin[(size_t)b * 512 + tid];
    hc[256 + tid] = dfin[(size_t)b * 512 + 256 + tid];
    hc[512 + tid] = cfin[(size_t)b * 512 + tid];
    hc[768 + tid] = cfin[(size_t)b * 512 + 256 + tid];
    __syncthreads();
    float part = 0.f;
#pragma unroll
    for (int pi = 0; pi < 2; ++pi) {
        int p = tid + pi * 256;
        float acc = Wyb[p];
        const float* wr = Wy + (size_t)p * 1024;
#pragma unroll 4
        for (int k = 0; k < 1024; k += 4) {
            float4 w = *reinterpret_cast<const float4*>(&wr[k]);
            acc = fmaf(hc[k], w.x, acc);
            acc = fmaf(hc[k + 1], w.y, acc);
            acc = fmaf(hc[k + 2], w.z, acc);
            acc = fmaf(hc[k + 3], w.w, acc);
        }
        part += acc * vy[p];
    }
#pragma unroll
    for (int off = 32; off; off >>= 1) part += __shfl_xor(part, off);
    const int lane = tid & 63, wid = tid >> 6;
    if (lane == 0) sred[wid] = part;
    __syncthreads();
    if (tid == 0) out[b] = sred[0] + sred[1] + sred[2] + sred[3] + vyb[0];
}

extern "C" void kernel_launch(void* const* d_in, const int* in_sizes, int n_in,
                              void* d_out, int out_size, void* d_ws, size_t ws_size,
                              hipStream_t stream) {
    const float* enc = (const float*)d_in[0];
    const float* yin = (const float*)d_in[1];
    const float* Wdw = (const float*)d_in[2];
    const float* Wdb = (const float*)d_in[3];
    const float* Udw = (const float*)d_in[4];
    const float* vdw = (const float*)d_in[5];
    const float* wtw = (const float*)d_in[6];
    const float* wtb = (const float*)d_in[7];
    const float* Wyw = (const float*)d_in[8];
    const float* Wyb = (const float*)d_in[9];
    const float* vyw = (const float*)d_in[10];
    const float* vyb = (const float*)d_in[11];
    const float* Wih = (const float*)d_in[12];
    const float* Whh = (const float*)d_in[13];
    const float* bih = (const float*)d_in[14];
    const float* bhh = (const float*)d_in[15];
    float* out = (float*)d_out;
    const int N = Bsz * Psz;   // 262144

    // workspace: Uyh | W16 | bf16 states | f32 scratch | ewt
    char* p = (char*)d_ws;
    unsigned short* Uyh = (unsigned short*)p;  p += (size_t)Bsz * Tsz * Msz * 2;   // 64 MB
    unsigned short* W16 = (unsigned short*)p;  p += (size_t)3072 * 512 * 2;        // 3 MB
    unsigned short* dbh = (unsigned short*)p;  p += (size_t)2 * N * 2;             // 1 MB
    unsigned short* sbh = (unsigned short*)p;  p += (size_t)2 * N * 2;             // 1 MB
    float* dbuf = (float*)p;  p += (size_t)2 * N * 4;                              // 2 MB
    float* sbuf = (float*)p;  p += (size_t)2 * N * 4;                              // 2 MB
    float* x1g  = (float*)p;  p += (size_t)N * 4;                                  // 1 MB
    float* cb   = (float*)p;  p += (size_t)N * 4;                                  // 1 MB
    float* gacc = (float*)p;  p += (size_t)Bsz * 2048 * 4;                         // 4 MB
    float* ewt  = (float*)p;  p += (size_t)Bsz * Tsz * 4;                          // 256 KB

    k_uy<<<dim3(Msz / 64, (Bsz * Tsz) / 64), 256, 0, stream>>>(enc, Udw, Uyh);
    k_ewt<<<(Bsz * Tsz) / 4, 256, 0, stream>>>(enc, wtw, ewt);
    k_w2b<<<(3072 * 512) / (256 * 8), 256, 0, stream>>>(Whh, Wdw, W16);
    k_zero<<<(N + 255) / 256, 256, 0, stream>>>(dbuf, sbuf, dbh, sbh, N);

    for (int t = 0; t < Tsz; ++t) {
        const int c = t & 1, n = c ^ 1;
        k_mm<<<dim3(40, 8), 256, 0, stream>>>(dbh + (size_t)c * N, sbh + (size_t)c * N,
                                              W16, Wdb, gacc, x1g);
        k_attn3<<<Bsz, 512, 0, stream>>>(Uyh, enc, ewt, x1g, vdw, wtw, wtb, yin,
                                         gacc, Wih, bih, bhh,
                                         sbuf + (size_t)c * N,
                                         sbuf + (size_t)n * N, dbuf + (size_t)n * N,
                                         sbh + (size_t)n * N, dbh + (size_t)n * N,
                                         cb, t);
    }
    // after 128 steps live parity is 0
    k_final<<<Bsz, 256, 0, stream>>>(dbuf, cb, Wyw, Wyb, vyw, vyb, out);
}